// Round 1
// baseline (238.116 us; speedup 1.0000x reference)
//
#include <hip/hip_runtime.h>
#include <hip/hip_bf16.h>
#include <cstdint>
#include <cstddef>

#define EMBED 768
#define NSEQ 1024
#define BATCH 8
#define HEADS 12
#define HDIM 64
#define BH (BATCH*HEADS)      // 96
#define MROWS (BATCH*NSEQ)    // 8192

typedef __attribute__((ext_vector_type(8))) short bf16x8;
typedef __attribute__((ext_vector_type(4))) short s16x4;
typedef __attribute__((ext_vector_type(4))) float f32x4;

__device__ __forceinline__ short f2bf(float f) {
    __hip_bfloat16 h = __float2bfloat16(f);
    return __builtin_bit_cast(short, h);
}

#define GLD_LDS(g, l) __builtin_amdgcn_global_load_lds( \
    (const __attribute__((address_space(1))) void*)(g), \
    (__attribute__((address_space(3))) void*)(l), 16, 0, 0)

// ---------------- conversion kernels ----------------

__global__ __launch_bounds__(256) void cvt_x_kernel(const float* __restrict__ x,
                                                    short* __restrict__ xb, int n) {
    int stride = gridDim.x * blockDim.x * 4;
    for (int i = (blockIdx.x * blockDim.x + threadIdx.x) * 4; i < n; i += stride) {
        float4 v = *reinterpret_cast<const float4*>(x + i);
        s16x4 o;
        o[0] = f2bf(v.x); o[1] = f2bf(v.y); o[2] = f2bf(v.z); o[3] = f2bf(v.w);
        *reinterpret_cast<s16x4*>(xb + i) = o;
    }
}

// W [768][768] fp32 (row = in/k, col = out/n)  ->  Wt [768][768] bf16 (row = n, col = k)
__global__ __launch_bounds__(256) void transpose_w_kernel(
        const float* __restrict__ W0, const float* __restrict__ W1,
        const float* __restrict__ W2, const float* __restrict__ W3,
        short* __restrict__ T0, short* __restrict__ T1,
        short* __restrict__ T2, short* __restrict__ T3) {
    const float* W; short* T;
    switch (blockIdx.z) {
        case 0: W = W0; T = T0; break;
        case 1: W = W1; T = T1; break;
        case 2: W = W2; T = T2; break;
        default: W = W3; T = T3; break;
    }
    __shared__ float tile[32][33];
    int n0 = blockIdx.x * 32, k0 = blockIdx.y * 32;
    int tx = threadIdx.x & 31, ty = threadIdx.x >> 5;   // ty: 0..7
    #pragma unroll
    for (int r = 0; r < 4; r++)
        tile[ty + r*8][tx] = W[(size_t)(k0 + ty + r*8) * EMBED + n0 + tx];
    __syncthreads();
    #pragma unroll
    for (int r = 0; r < 4; r++)
        T[(size_t)(n0 + ty + r*8) * EMBED + k0 + tx] = f2bf(tile[tx][ty + r*8]);
}

// ---------------- 128x128 bf16 MFMA GEMM (m97 structure) ----------------
// A: [M][768] bf16 row-major. Bt: [N][768] bf16 (i.e. W^T so reads are K-contiguous).
// MODE 0: out = bf16 head-layout [B,H,N,64], val=(acc+bias)*scale
// MODE 1: out = fp32 [M][N],               val= acc+bias
template<int MODE>
__global__ __launch_bounds__(256) void gemm128_kernel(
        const short* __restrict__ A, const short* __restrict__ Bt,
        const float* __restrict__ bias, void* __restrict__ out, float scale) {
    __shared__ short Alds[128 * 32];
    __shared__ short Blds[128 * 32];
    const int m0 = blockIdx.x * 128;
    const int n0 = blockIdx.y * 128;
    const int t = threadIdx.x;
    const int l = t & 63, w = t >> 6;
    const int wm = (w >> 1) * 64, wn = (w & 1) * 64;
    const int lr = l & 15, lg = l >> 4;

    f32x4 acc[4][4] = {};
    const int arow = t >> 2, aseg = t & 3;

    for (int k0 = 0; k0 < EMBED; k0 += 32) {
        __syncthreads();
        #pragma unroll
        for (int p = 0; p < 2; ++p) {
            int row = arow + p * 64;
            GLD_LDS(A  + (size_t)(m0 + row) * EMBED + k0 + aseg * 8, Alds + row * 32 + aseg * 8);
            GLD_LDS(Bt + (size_t)(n0 + row) * EMBED + k0 + aseg * 8, Blds + row * 32 + aseg * 8);
        }
        __syncthreads();
        bf16x8 af[4], bfr[4];
        #pragma unroll
        for (int i = 0; i < 4; i++)
            af[i] = *reinterpret_cast<const bf16x8*>(Alds + (wm + i*16 + lr) * 32 + lg * 8);
        #pragma unroll
        for (int j = 0; j < 4; j++)
            bfr[j] = *reinterpret_cast<const bf16x8*>(Blds + (wn + j*16 + lr) * 32 + lg * 8);
        #pragma unroll
        for (int i = 0; i < 4; i++)
            #pragma unroll
            for (int j = 0; j < 4; j++)
                acc[i][j] = __builtin_amdgcn_mfma_f32_16x16x32_bf16(af[i], bfr[j], acc[i][j], 0, 0, 0);
    }

    #pragma unroll
    for (int i = 0; i < 4; i++) {
        #pragma unroll
        for (int j = 0; j < 4; j++) {
            int n = n0 + wn + j * 16 + lr;
            float b = bias[n];
            #pragma unroll
            for (int r = 0; r < 4; r++) {
                int m = m0 + wm + i * 16 + lg * 4 + r;
                float v = (acc[i][j][r] + b) * scale;
                if (MODE == 0) {
                    int bi = m >> 10, seq = m & 1023, h = n >> 6, hd = n & 63;
                    ((short*)out)[((size_t)(bi * HEADS + h) * NSEQ + seq) * HDIM + hd] = f2bf(v);
                } else {
                    ((float*)out)[(size_t)m * EMBED + n] = v;
                }
            }
        }
    }
}

// ---------------- flash attention ----------------
// Qh/Kh/Vh: [96][1024][64] bf16 (Q pre-scaled by 1/8). ctx out: [8192][768] bf16.
__global__ __launch_bounds__(256) void attn_kernel(
        const short* __restrict__ Qh, const short* __restrict__ Kh,
        const short* __restrict__ Vh, short* __restrict__ ctx) {
    __shared__ short Klds[64 * 64];     // [key][hd]
    __shared__ short Vt[64 * 64];       // [hd][key]
    __shared__ short Plds[4][16 * 64];  // per-wave [qrow][key]

    const int bid = blockIdx.x;
    const int bh = bid >> 4;            // 0..95
    const int q0 = (bid & 15) * 64;
    const int t = threadIdx.x, l = t & 63, w = t >> 6;
    const int lr = l & 15, lg = l >> 4;
    const size_t headbase = (size_t)bh * NSEQ;

    // Q fragments held in registers the whole kernel
    bf16x8 aq[2];
    {
        const short* qb = Qh + (headbase + q0 + w * 16 + lr) * HDIM + lg * 8;
        aq[0] = *reinterpret_cast<const bf16x8*>(qb);
        aq[1] = *reinterpret_cast<const bf16x8*>(qb + 32);
    }

    f32x4 accc[4] = {};                 // ctx accum per hd-tile
    float mrun[4], lrun[4];
    #pragma unroll
    for (int r = 0; r < 4; r++) { mrun[r] = -1e30f; lrun[r] = 0.f; }

    for (int kt0 = 0; kt0 < NSEQ; kt0 += 64) {
        __syncthreads();
        // stage K [64][64] via global_load_lds (linear)
        #pragma unroll
        for (int p = 0; p < 2; ++p) {
            int row = (t >> 3) + p * 32, seg = t & 7;
            GLD_LDS(Kh + (headbase + kt0 + row) * HDIM + seg * 8, Klds + row * 64 + seg * 8);
        }
        // stage V transposed via registers
        #pragma unroll
        for (int p = 0; p < 2; ++p) {
            int key = (t >> 3) + p * 32, seg = t & 7;
            bf16x8 v = *reinterpret_cast<const bf16x8*>(Vh + (headbase + kt0 + key) * HDIM + seg * 8);
            #pragma unroll
            for (int j = 0; j < 8; j++) Vt[(seg * 8 + j) * 64 + key] = v[j];
        }
        __syncthreads();

        // S = Q K^T for this wave's 16 q-rows x 64 keys
        f32x4 s[4];
        #pragma unroll
        for (int kt = 0; kt < 4; kt++) {
            const short* kb = Klds + (kt * 16 + lr) * 64 + lg * 8;
            bf16x8 bk0 = *reinterpret_cast<const bf16x8*>(kb);
            bf16x8 bk1 = *reinterpret_cast<const bf16x8*>(kb + 32);
            f32x4 z = {};
            z = __builtin_amdgcn_mfma_f32_16x16x32_bf16(aq[0], bk0, z, 0, 0, 0);
            z = __builtin_amdgcn_mfma_f32_16x16x32_bf16(aq[1], bk1, z, 0, 0, 0);
            s[kt] = z;
        }

        // online softmax (wave-parallel, reductions across the 16 lanes of each row group)
        #pragma unroll
        for (int r = 0; r < 4; r++) {
            float m = fmaxf(fmaxf(s[0][r], s[1][r]), fmaxf(s[2][r], s[3][r]));
            #pragma unroll
            for (int mk = 1; mk < 16; mk <<= 1) m = fmaxf(m, __shfl_xor(m, mk, 16));
            float mnew = fmaxf(mrun[r], m);
            float alpha = __expf(mrun[r] - mnew);
            mrun[r] = mnew;
            float ts = 0.f;
            #pragma unroll
            for (int kt = 0; kt < 4; kt++) {
                float p_ = __expf(s[kt][r] - mnew);
                s[kt][r] = p_;
                ts += p_;
            }
            #pragma unroll
            for (int mk = 1; mk < 16; mk <<= 1) ts += __shfl_xor(ts, mk, 16);
            lrun[r] = lrun[r] * alpha + ts;
            #pragma unroll
            for (int ht = 0; ht < 4; ht++) accc[ht][r] *= alpha;
        }

        // P -> LDS (bf16), transposing from C-layout to A-operand layout
        short* pw = &Plds[w][0];
        #pragma unroll
        for (int kt = 0; kt < 4; kt++)
            #pragma unroll
            for (int r = 0; r < 4; r++)
                pw[(lg * 4 + r) * 64 + kt * 16 + lr] = f2bf(s[kt][r]);

        // PV
        bf16x8 pa0 = *reinterpret_cast<const bf16x8*>(pw + lr * 64 + lg * 8);
        bf16x8 pa1 = *reinterpret_cast<const bf16x8*>(pw + lr * 64 + lg * 8 + 32);
        #pragma unroll
        for (int ht = 0; ht < 4; ht++) {
            const short* vb = Vt + (ht * 16 + lr) * 64 + lg * 8;
            bf16x8 bv0 = *reinterpret_cast<const bf16x8*>(vb);
            bf16x8 bv1 = *reinterpret_cast<const bf16x8*>(vb + 32);
            accc[ht] = __builtin_amdgcn_mfma_f32_16x16x32_bf16(pa0, bv0, accc[ht], 0, 0, 0);
            accc[ht] = __builtin_amdgcn_mfma_f32_16x16x32_bf16(pa1, bv1, accc[ht], 0, 0, 0);
        }
    }

    // epilogue: ctx[b, q, h*64+hd] = acc / l
    int b = bh / HEADS, h = bh % HEADS;
    #pragma unroll
    for (int ht = 0; ht < 4; ht++) {
        #pragma unroll
        for (int r = 0; r < 4; r++) {
            int q = q0 + w * 16 + lg * 4 + r;
            float v = accc[ht][r] / lrun[r];
            ctx[((size_t)b * NSEQ + q) * EMBED + h * HDIM + ht * 16 + lr] = f2bf(v);
        }
    }
}

// ---------------- launch ----------------

extern "C" void kernel_launch(void* const* d_in, const int* in_sizes, int n_in,
                              void* d_out, int out_size, void* d_ws, size_t ws_size,
                              hipStream_t stream) {
    (void)in_sizes; (void)n_in; (void)out_size; (void)ws_size;
    const float* x  = (const float*)d_in[0];
    const float* Wq = (const float*)d_in[1];
    const float* bq = (const float*)d_in[2];
    const float* Wk = (const float*)d_in[3];
    const float* bk = (const float*)d_in[4];
    const float* Wv = (const float*)d_in[5];
    const float* bv = (const float*)d_in[6];
    const float* Wo = (const float*)d_in[7];
    const float* bo = (const float*)d_in[8];
    float* out = (float*)d_out;

    char* ws = (char*)d_ws;
    size_t off = 0;
    short* xb  = (short*)(ws + off); off += (size_t)MROWS * EMBED * 2;
    short* Wtq = (short*)(ws + off); off += (size_t)EMBED * EMBED * 2;
    short* Wtk = (short*)(ws + off); off += (size_t)EMBED * EMBED * 2;
    short* Wtv = (short*)(ws + off); off += (size_t)EMBED * EMBED * 2;
    short* Wto = (short*)(ws + off); off += (size_t)EMBED * EMBED * 2;
    short* Qh  = (short*)(ws + off); off += (size_t)BH * NSEQ * HDIM * 2;
    short* Kh  = (short*)(ws + off); off += (size_t)BH * NSEQ * HDIM * 2;
    short* Vh  = (short*)(ws + off); off += (size_t)BH * NSEQ * HDIM * 2;
    short* ctx = (short*)(ws + off); off += (size_t)MROWS * EMBED * 2;

    cvt_x_kernel<<<2048, 256, 0, stream>>>(x, xb, MROWS * EMBED);
    dim3 gt(EMBED / 32, EMBED / 32, 4);
    transpose_w_kernel<<<gt, 256, 0, stream>>>(Wq, Wk, Wv, Wo, Wtq, Wtk, Wtv, Wto);

    dim3 gg(MROWS / 128, EMBED / 128);
    gemm128_kernel<0><<<gg, 256, 0, stream>>>(xb, Wtq, bq, Qh, 0.125f);
    gemm128_kernel<0><<<gg, 256, 0, stream>>>(xb, Wtk, bk, Kh, 1.0f);
    gemm128_kernel<0><<<gg, 256, 0, stream>>>(xb, Wtv, bv, Vh, 1.0f);

    attn_kernel<<<BH * (NSEQ / 64), 256, 0, stream>>>(Qh, Kh, Vh, ctx);

    gemm128_kernel<1><<<gg, 256, 0, stream>>>(ctx, Wto, bo, out, 1.0f);
}

// Round 2
// 145.853 us; speedup vs baseline: 1.6326x; 1.6326x over previous
//
#include <hip/hip_runtime.h>
#include <hip/hip_bf16.h>
#include <cstdint>
#include <cstddef>

#define EMBED 768
#define NSEQ 1024
#define BATCH 8
#define HEADS 12
#define HDIM 64
#define BH (BATCH*HEADS)      // 96
#define MROWS (BATCH*NSEQ)    // 8192

typedef __attribute__((ext_vector_type(8))) short bf16x8;
typedef __attribute__((ext_vector_type(4))) short s16x4;
typedef __attribute__((ext_vector_type(4))) float f32x4;

__device__ __forceinline__ short f2bf(float f) {
    __hip_bfloat16 h = __float2bfloat16(f);
    return __builtin_bit_cast(short, h);
}

#define GLD_LDS(g, l) __builtin_amdgcn_global_load_lds( \
    (const __attribute__((address_space(1))) void*)(g), \
    (__attribute__((address_space(3))) void*)(l), 16, 0, 0)

#define MFMA32(a, b, c) __builtin_amdgcn_mfma_f32_16x16x32_bf16((a), (b), (c), 0, 0, 0)

// ---------------- conversion kernels ----------------

__global__ __launch_bounds__(256) void cvt_x_kernel(const float* __restrict__ x,
                                                    short* __restrict__ xb, int n) {
    int stride = gridDim.x * blockDim.x * 4;
    for (int i = (blockIdx.x * blockDim.x + threadIdx.x) * 4; i < n; i += stride) {
        float4 v = *reinterpret_cast<const float4*>(x + i);
        s16x4 o;
        o[0] = f2bf(v.x); o[1] = f2bf(v.y); o[2] = f2bf(v.z); o[3] = f2bf(v.w);
        *reinterpret_cast<s16x4*>(xb + i) = o;
    }
}

// W [768][768] fp32 (row = in/k, col = out/n)  ->  Wt [768][768] bf16 (row = n, col = k)
__global__ __launch_bounds__(256) void transpose_w_kernel(
        const float* __restrict__ W0, const float* __restrict__ W1,
        const float* __restrict__ W2, const float* __restrict__ W3,
        short* __restrict__ T0, short* __restrict__ T1,
        short* __restrict__ T2, short* __restrict__ T3) {
    const float* W; short* T;
    switch (blockIdx.z) {
        case 0: W = W0; T = T0; break;
        case 1: W = W1; T = T1; break;
        case 2: W = W2; T = T2; break;
        default: W = W3; T = T3; break;
    }
    __shared__ float tile[32][33];
    int n0 = blockIdx.x * 32, k0 = blockIdx.y * 32;
    int tx = threadIdx.x & 31, ty = threadIdx.x >> 5;   // ty: 0..7
    #pragma unroll
    for (int r = 0; r < 4; r++)
        tile[ty + r*8][tx] = W[(size_t)(k0 + ty + r*8) * EMBED + n0 + tx];
    __syncthreads();
    #pragma unroll
    for (int r = 0; r < 4; r++)
        T[(size_t)(n0 + ty + r*8) * EMBED + k0 + tx] = f2bf(tile[tx][ty + r*8]);
}

// ---------------- 128x128 bf16 MFMA GEMM ----------------
// A: [M][768] bf16 row-major. Bt: [N][768] bf16 (W^T, K-contiguous).
// MODE 0: out = bf16 head-layout [B,H,N,64], val=(acc+bias)*scale
// MODE 1: out = fp32 [M][N]
// MODE 2: out = bf16 transposed head-layout [B,H,64,N] (for V)
template<int MODE>
__global__ __launch_bounds__(256) void gemm128_kernel(
        const short* __restrict__ A, const short* __restrict__ Bt,
        const float* __restrict__ bias, void* __restrict__ out, float scale) {
    __shared__ short Alds[128 * 32];
    __shared__ short Blds[128 * 32];
    const int m0 = blockIdx.x * 128;
    const int n0 = blockIdx.y * 128;
    const int t = threadIdx.x;
    const int l = t & 63, w = t >> 6;
    const int wm = (w >> 1) * 64, wn = (w & 1) * 64;
    const int lr = l & 15, lg = l >> 4;

    f32x4 acc[4][4] = {};
    const int arow = t >> 2, aseg = t & 3;

    for (int k0 = 0; k0 < EMBED; k0 += 32) {
        __syncthreads();
        #pragma unroll
        for (int p = 0; p < 2; ++p) {
            int row = arow + p * 64;
            GLD_LDS(A  + (size_t)(m0 + row) * EMBED + k0 + aseg * 8, Alds + row * 32 + aseg * 8);
            GLD_LDS(Bt + (size_t)(n0 + row) * EMBED + k0 + aseg * 8, Blds + row * 32 + aseg * 8);
        }
        __syncthreads();
        bf16x8 af[4], bfr[4];
        #pragma unroll
        for (int i = 0; i < 4; i++)
            af[i] = *reinterpret_cast<const bf16x8*>(Alds + (wm + i*16 + lr) * 32 + lg * 8);
        #pragma unroll
        for (int j = 0; j < 4; j++)
            bfr[j] = *reinterpret_cast<const bf16x8*>(Blds + (wn + j*16 + lr) * 32 + lg * 8);
        #pragma unroll
        for (int i = 0; i < 4; i++)
            #pragma unroll
            for (int j = 0; j < 4; j++)
                acc[i][j] = MFMA32(af[i], bfr[j], acc[i][j]);
    }

    #pragma unroll
    for (int i = 0; i < 4; i++) {
        #pragma unroll
        for (int j = 0; j < 4; j++) {
            int n = n0 + wn + j * 16 + lr;
            float b = bias[n];
            if (MODE == 2) {
                int mbase = m0 + wm + i * 16 + lg * 4;
                int bi = mbase >> 10, seq = mbase & 1023;
                int h = n >> 6, hd = n & 63;
                s16x4 pk;
                #pragma unroll
                for (int r = 0; r < 4; r++) pk[r] = f2bf(acc[i][j][r] + b);
                *reinterpret_cast<s16x4*>((short*)out +
                    ((size_t)((bi * HEADS + h) * HDIM + hd)) * NSEQ + seq) = pk;
            } else {
                #pragma unroll
                for (int r = 0; r < 4; r++) {
                    int m = m0 + wm + i * 16 + lg * 4 + r;
                    float v = (acc[i][j][r] + b) * scale;
                    if (MODE == 0) {
                        int bi = m >> 10, seq = m & 1023, h = n >> 6, hd = n & 63;
                        ((short*)out)[((size_t)(bi * HEADS + h) * NSEQ + seq) * HDIM + hd] = f2bf(v);
                    } else {
                        ((float*)out)[(size_t)m * EMBED + n] = v;
                    }
                }
            }
        }
    }
}

// ---------------- flash attention (swapped-QK^T, swizzled LDS, 2-phase) ----------------
// Qh/Kh: [96][1024][64] bf16 (Q pre-scaled by 1/8). Vtg: [96][64][1024] bf16.
// ctx out: [8192][768] bf16.
__global__ __launch_bounds__(256, 4) void attn_kernel(
        const short* __restrict__ Qh, const short* __restrict__ Kh,
        const short* __restrict__ Vtg, short* __restrict__ ctx) {
    __shared__ short Klds[2][64 * 64];   // [key][hd], 16B-chunk XOR-swizzled by key&7
    __shared__ short Vlds[2][64 * 64];   // [hd][key], 16B-chunk XOR-swizzled by hd&7
    __shared__ short Plds[4][16 * 64];   // per-wave P[q][k], swizzled by q&7

    const int bid = blockIdx.x;
    const int bh = bid % BH;             // XCD-affinity: all 16 q-blocks of a head share bid%8
    const int q0 = (bid / BH) * 64;
    const int t = threadIdx.x, l = t & 63, w = t >> 6;
    const int lr = l & 15, lg = l >> 4;
    const int pmask = lr & 7;
    const size_t headbase = (size_t)bh * NSEQ;

    // Q fragment (B-operand of swapped QK^T): Q[q = q0+w*16+lr][d = lg*8..+7]
    bf16x8 aq0, aq1;
    {
        const short* qb = Qh + (headbase + q0 + w * 16 + lr) * HDIM + lg * 8;
        aq0 = *reinterpret_cast<const bf16x8*>(qb);
        aq1 = *reinterpret_cast<const bf16x8*>(qb + 32);
    }

    const int srow = t >> 3, sseg = t & 7;   // staging: 2 rounds of 32 rows x 8 chunks

    auto stage = [&](int bufb, int kt0) {
        #pragma unroll
        for (int p = 0; p < 2; p++) {
            int row = srow + p * 32;
            int sw = (sseg ^ (row & 7)) << 3;    // pre-swizzled global chunk (involution)
            GLD_LDS(Kh + (headbase + kt0 + row) * HDIM + sw,
                    &Klds[bufb][row * 64 + sseg * 8]);
            GLD_LDS(Vtg + (((size_t)(bh * HDIM + row)) << 10) + kt0 + sw,
                    &Vlds[bufb][row * 64 + sseg * 8]);
        }
    };

    f32x4 accc[4] = {};      // ctx[q = lg*4+r (within wave 16)][hd = ht*16+lr]
    float mrun = -1e30f, lrun = 0.f;   // per-lane stats for q = lr

    stage(0, 0);
    __syncthreads();

    int cur = 0;
    for (int it = 0; it < NSEQ / 64; ++it) {
        if (it + 1 < NSEQ / 64) stage(cur ^ 1, (it + 1) * 64);

        // S^T[k][q] = K Q^T : lane holds s[kt][r] = S[q=lr][k = kt*16+lg*4+r]
        f32x4 s[4];
        const short* Kb = Klds[cur];
        __builtin_amdgcn_s_setprio(1);
        #pragma unroll
        for (int kt = 0; kt < 4; kt++) {
            const short* kb = Kb + (kt * 16 + lr) * 64;
            bf16x8 ak0 = *reinterpret_cast<const bf16x8*>(kb + ((lg ^ pmask) << 3));
            bf16x8 ak1 = *reinterpret_cast<const bf16x8*>(kb + (((lg + 4) ^ pmask) << 3));
            f32x4 z = {};
            z = MFMA32(ak0, aq0, z);
            z = MFMA32(ak1, aq1, z);
            s[kt] = z;
        }
        __builtin_amdgcn_s_setprio(0);

        // online softmax, fully in-register (row q = lr lives in 4 lanes: lr, lr+16, lr+32, lr+48)
        float mx = s[0][0];
        #pragma unroll
        for (int kt = 0; kt < 4; kt++)
            #pragma unroll
            for (int r = 0; r < 4; r++) mx = fmaxf(mx, s[kt][r]);
        mx = fmaxf(mx, __shfl_xor(mx, 16));
        mx = fmaxf(mx, __shfl_xor(mx, 32));
        float mnew = fmaxf(mrun, mx);
        float alpha = __expf(mrun - mnew);
        mrun = mnew;
        float ts = 0.f;
        #pragma unroll
        for (int kt = 0; kt < 4; kt++)
            #pragma unroll
            for (int r = 0; r < 4; r++) {
                float p_ = __expf(s[kt][r] - mnew);
                s[kt][r] = p_;
                ts += p_;
            }
        ts += __shfl_xor(ts, 16);
        ts += __shfl_xor(ts, 32);
        lrun = lrun * alpha + ts;

        // rescale accumulator: need alpha for q = lg*4+r  (held by lane lr=lg*4+r)
        #pragma unroll
        for (int r = 0; r < 4; r++) {
            float ar = __shfl(alpha, (lg << 4) | (lg * 4 + r));
            #pragma unroll
            for (int ht = 0; ht < 4; ht++) accc[ht][r] *= ar;
        }

        // pack P -> per-wave LDS in A-operand layout P[q][k], swizzled, 8B writes
        short* pw = &Plds[w][0];
        #pragma unroll
        for (int kt = 0; kt < 4; kt++) {
            s16x4 pk;
            #pragma unroll
            for (int r = 0; r < 4; r++) pk[r] = f2bf(s[kt][r]);
            int chunk = kt * 2 + (lg >> 1);
            *reinterpret_cast<s16x4*>(pw + lr * 64 + (((chunk ^ pmask)) << 3) + ((lg & 1) << 2)) = pk;
        }

        // PV: D[q][hd] += P[q][k] V[k][hd]
        const short* Vb = Vlds[cur];
        #pragma unroll
        for (int kb = 0; kb < 2; kb++) {
            bf16x8 pa = *reinterpret_cast<const bf16x8*>(pw + lr * 64 + (((kb * 4 + lg) ^ pmask) << 3));
            __builtin_amdgcn_s_setprio(1);
            #pragma unroll
            for (int ht = 0; ht < 4; ht++) {
                const short* vb = Vb + (ht * 16 + lr) * 64 + (((kb * 4 + lg) ^ pmask) << 3);
                bf16x8 bv = *reinterpret_cast<const bf16x8*>(vb);
                accc[ht] = MFMA32(pa, bv, accc[ht]);
            }
            __builtin_amdgcn_s_setprio(0);
        }

        __syncthreads();
        cur ^= 1;
    }

    // epilogue: ctx[b, q, h*64 + ht*16 + lr] = acc / l(q),  q = q0 + w*16 + lg*4 + r
    int b = bh / HEADS, h = bh % HEADS;
    #pragma unroll
    for (int r = 0; r < 4; r++) {
        float linv = 1.f / __shfl(lrun, (lg << 4) | (lg * 4 + r));
        int q = q0 + w * 16 + lg * 4 + r;
        #pragma unroll
        for (int ht = 0; ht < 4; ht++)
            ctx[((size_t)b * NSEQ + q) * EMBED + h * HDIM + ht * 16 + lr] = f2bf(accc[ht][r] * linv);
    }
}

// ---------------- launch ----------------

extern "C" void kernel_launch(void* const* d_in, const int* in_sizes, int n_in,
                              void* d_out, int out_size, void* d_ws, size_t ws_size,
                              hipStream_t stream) {
    (void)in_sizes; (void)n_in; (void)out_size; (void)ws_size;
    const float* x  = (const float*)d_in[0];
    const float* Wq = (const float*)d_in[1];
    const float* bq = (const float*)d_in[2];
    const float* Wk = (const float*)d_in[3];
    const float* bk = (const float*)d_in[4];
    const float* Wv = (const float*)d_in[5];
    const float* bv = (const float*)d_in[6];
    const float* Wo = (const float*)d_in[7];
    const float* bo = (const float*)d_in[8];
    float* out = (float*)d_out;

    char* ws = (char*)d_ws;
    size_t off = 0;
    short* xb  = (short*)(ws + off); off += (size_t)MROWS * EMBED * 2;
    short* Wtq = (short*)(ws + off); off += (size_t)EMBED * EMBED * 2;
    short* Wtk = (short*)(ws + off); off += (size_t)EMBED * EMBED * 2;
    short* Wtv = (short*)(ws + off); off += (size_t)EMBED * EMBED * 2;
    short* Wto = (short*)(ws + off); off += (size_t)EMBED * EMBED * 2;
    short* Qh  = (short*)(ws + off); off += (size_t)BH * NSEQ * HDIM * 2;
    short* Kh  = (short*)(ws + off); off += (size_t)BH * NSEQ * HDIM * 2;
    short* Vtg = (short*)(ws + off); off += (size_t)BH * NSEQ * HDIM * 2;
    short* ctx = (short*)(ws + off); off += (size_t)MROWS * EMBED * 2;

    cvt_x_kernel<<<2048, 256, 0, stream>>>(x, xb, MROWS * EMBED);
    dim3 gt(EMBED / 32, EMBED / 32, 4);
    transpose_w_kernel<<<gt, 256, 0, stream>>>(Wq, Wk, Wv, Wo, Wtq, Wtk, Wtv, Wto);

    dim3 gg(MROWS / 128, EMBED / 128);
    gemm128_kernel<0><<<gg, 256, 0, stream>>>(xb, Wtq, bq, Qh, 0.125f);
    gemm128_kernel<0><<<gg, 256, 0, stream>>>(xb, Wtk, bk, Kh, 1.0f);
    gemm128_kernel<2><<<gg, 256, 0, stream>>>(xb, Wtv, bv, Vtg, 1.0f);

    attn_kernel<<<BH * (NSEQ / 64), 256, 0, stream>>>(Qh, Kh, Vtg, ctx);

    gemm128_kernel<1><<<gg, 256, 0, stream>>>(ctx, Wto, bo, out, 1.0f);
}

// Round 3
// 133.167 us; speedup vs baseline: 1.7881x; 1.0953x over previous
//
#include <hip/hip_runtime.h>
#include <hip/hip_bf16.h>
#include <cstdint>
#include <cstddef>

#define EMBED 768
#define NSEQ 1024
#define BATCH 8
#define HEADS 12
#define HDIM 64
#define BH (BATCH*HEADS)      // 96
#define MROWS (BATCH*NSEQ)    // 8192

typedef __attribute__((ext_vector_type(8))) short bf16x8;
typedef __attribute__((ext_vector_type(4))) short s16x4;
typedef __attribute__((ext_vector_type(4))) float f32x4;

__device__ __forceinline__ short f2bf(float f) {
    __hip_bfloat16 h = __float2bfloat16(f);
    return __builtin_bit_cast(short, h);
}

__device__ __forceinline__ float fexp2(float x) {
#if __has_builtin(__builtin_amdgcn_exp2f)
    return __builtin_amdgcn_exp2f(x);
#else
    return exp2f(x);
#endif
}

#define GLD_LDS(g, l) __builtin_amdgcn_global_load_lds( \
    (const __attribute__((address_space(1))) void*)(g), \
    (__attribute__((address_space(3))) void*)(l), 16, 0, 0)

#define MFMA32(a, b, c) __builtin_amdgcn_mfma_f32_16x16x32_bf16((a), (b), (c), 0, 0, 0)

#define QSCALE 0.180336881f   /* (1/8) * log2(e): S computed directly in log2 domain */

// ---------------- conversion kernels ----------------

__global__ __launch_bounds__(256) void cvt_x_kernel(const float* __restrict__ x,
                                                    short* __restrict__ xb, int n) {
    int stride = gridDim.x * blockDim.x * 4;
    for (int i = (blockIdx.x * blockDim.x + threadIdx.x) * 4; i < n; i += stride) {
        float4 v = *reinterpret_cast<const float4*>(x + i);
        s16x4 o;
        o[0] = f2bf(v.x); o[1] = f2bf(v.y); o[2] = f2bf(v.z); o[3] = f2bf(v.w);
        *reinterpret_cast<s16x4*>(xb + i) = o;
    }
}

// W [768][768] fp32 (row = in/k, col = out/n)  ->  Wt [768][768] bf16 (row = n, col = k)
__global__ __launch_bounds__(256) void transpose_w_kernel(
        const float* __restrict__ W0, const float* __restrict__ W1,
        const float* __restrict__ W2, const float* __restrict__ W3,
        short* __restrict__ T0, short* __restrict__ T1,
        short* __restrict__ T2, short* __restrict__ T3) {
    const float* W; short* T;
    switch (blockIdx.z) {
        case 0: W = W0; T = T0; break;
        case 1: W = W1; T = T1; break;
        case 2: W = W2; T = T2; break;
        default: W = W3; T = T3; break;
    }
    __shared__ float tile[32][33];
    int n0 = blockIdx.x * 32, k0 = blockIdx.y * 32;
    int tx = threadIdx.x & 31, ty = threadIdx.x >> 5;   // ty: 0..7
    #pragma unroll
    for (int r = 0; r < 4; r++)
        tile[ty + r*8][tx] = W[(size_t)(k0 + ty + r*8) * EMBED + n0 + tx];
    __syncthreads();
    #pragma unroll
    for (int r = 0; r < 4; r++)
        T[(size_t)(n0 + ty + r*8) * EMBED + k0 + tx] = f2bf(tile[tx][ty + r*8]);
}

// ---------------- fused QKV GEMM: [8192 x 768] @ [768 x 2304] ----------------
// Bt rows 0..767 = Wq^T, 768..1535 = Wk^T, 1536..2303 = Wv^T (contiguous in ws).
// Q out: bf16 [B,H,N,64] scaled by QSCALE; K out: same layout; V out: bf16 [B,H,64,N].
__global__ __launch_bounds__(256) void gemm_qkv_kernel(
        const short* __restrict__ A, const short* __restrict__ Bt,
        const float* __restrict__ bq, const float* __restrict__ bk,
        const float* __restrict__ bv,
        short* __restrict__ Qh, short* __restrict__ Kh, short* __restrict__ Vtg) {
    __shared__ short Alds[128 * 32];
    __shared__ short Blds[128 * 32];
    // XCD-bijective swizzle (1152 % 8 == 0), n-fastest inside each XCD chunk:
    // B (3.5 MB) becomes L2-resident per XCD; A-panel (192 KB) hot across the n-sweep.
    const int id = blockIdx.x;
    const int flat = (id & 7) * 144 + (id >> 3);
    const int mi = flat / 18, ni = flat - mi * 18;
    const int m0 = mi * 128, n0 = ni * 128;

    const int t = threadIdx.x;
    const int l = t & 63, w = t >> 6;
    const int wm = (w >> 1) * 64, wn = (w & 1) * 64;
    const int lr = l & 15, lg = l >> 4;

    f32x4 acc[4][4] = {};
    const int arow = t >> 2, aseg = t & 3;

    for (int k0 = 0; k0 < EMBED; k0 += 32) {
        __syncthreads();
        #pragma unroll
        for (int p = 0; p < 2; ++p) {
            int row = arow + p * 64;
            GLD_LDS(A  + (size_t)(m0 + row) * EMBED + k0 + aseg * 8, Alds + row * 32 + aseg * 8);
            GLD_LDS(Bt + (size_t)(n0 + row) * EMBED + k0 + aseg * 8, Blds + row * 32 + aseg * 8);
        }
        __syncthreads();
        bf16x8 af[4], bfr[4];
        #pragma unroll
        for (int i = 0; i < 4; i++)
            af[i] = *reinterpret_cast<const bf16x8*>(Alds + (wm + i*16 + lr) * 32 + lg * 8);
        #pragma unroll
        for (int j = 0; j < 4; j++)
            bfr[j] = *reinterpret_cast<const bf16x8*>(Blds + (wn + j*16 + lr) * 32 + lg * 8);
        #pragma unroll
        for (int i = 0; i < 4; i++)
            #pragma unroll
            for (int j = 0; j < 4; j++)
                acc[i][j] = MFMA32(af[i], bfr[j], acc[i][j]);
    }

    #pragma unroll
    for (int j = 0; j < 4; j++) {
        const int nb = n0 + wn + j * 16;       // frag n-base; region uniform (768 % 16 == 0)
        const int reg = nb / 768;
        const int n = nb + lr;
        const int nn = n - reg * 768;
        const int h = nn >> 6, hd = nn & 63;
        const float b = (reg == 0) ? bq[nn] : (reg == 1) ? bk[nn] : bv[nn];
        const float scale = (reg == 0) ? QSCALE : 1.0f;
        #pragma unroll
        for (int i = 0; i < 4; i++) {
            const int mbase = m0 + wm + i * 16 + lg * 4;
            const int bi = mbase >> 10, seq = mbase & 1023;
            if (reg == 2) {
                s16x4 pk;
                #pragma unroll
                for (int r = 0; r < 4; r++) pk[r] = f2bf(acc[i][j][r] + b);
                *reinterpret_cast<s16x4*>(Vtg +
                    ((size_t)((bi * HEADS + h) * HDIM + hd)) * NSEQ + seq) = pk;
            } else {
                short* dst = (reg == 0) ? Qh : Kh;
                #pragma unroll
                for (int r = 0; r < 4; r++)
                    dst[((size_t)(bi * HEADS + h) * NSEQ + seq + r) * HDIM + hd] =
                        f2bf((acc[i][j][r] + b) * scale);
            }
        }
    }
}

// ---------------- 128x128 GEMM for the output projection ----------------
__global__ __launch_bounds__(256) void gemm_out_kernel(
        const short* __restrict__ A, const short* __restrict__ Bt,
        const float* __restrict__ bias, float* __restrict__ out) {
    __shared__ short Alds[128 * 32];
    __shared__ short Blds[128 * 32];
    const int m0 = blockIdx.x * 128;
    const int n0 = blockIdx.y * 128;
    const int t = threadIdx.x;
    const int l = t & 63, w = t >> 6;
    const int wm = (w >> 1) * 64, wn = (w & 1) * 64;
    const int lr = l & 15, lg = l >> 4;

    f32x4 acc[4][4] = {};
    const int arow = t >> 2, aseg = t & 3;

    for (int k0 = 0; k0 < EMBED; k0 += 32) {
        __syncthreads();
        #pragma unroll
        for (int p = 0; p < 2; ++p) {
            int row = arow + p * 64;
            GLD_LDS(A  + (size_t)(m0 + row) * EMBED + k0 + aseg * 8, Alds + row * 32 + aseg * 8);
            GLD_LDS(Bt + (size_t)(n0 + row) * EMBED + k0 + aseg * 8, Blds + row * 32 + aseg * 8);
        }
        __syncthreads();
        bf16x8 af[4], bfr[4];
        #pragma unroll
        for (int i = 0; i < 4; i++)
            af[i] = *reinterpret_cast<const bf16x8*>(Alds + (wm + i*16 + lr) * 32 + lg * 8);
        #pragma unroll
        for (int j = 0; j < 4; j++)
            bfr[j] = *reinterpret_cast<const bf16x8*>(Blds + (wn + j*16 + lr) * 32 + lg * 8);
        #pragma unroll
        for (int i = 0; i < 4; i++)
            #pragma unroll
            for (int j = 0; j < 4; j++)
                acc[i][j] = MFMA32(af[i], bfr[j], acc[i][j]);
    }

    #pragma unroll
    for (int i = 0; i < 4; i++) {
        #pragma unroll
        for (int j = 0; j < 4; j++) {
            int n = n0 + wn + j * 16 + lr;
            float b = bias[n];
            #pragma unroll
            for (int r = 0; r < 4; r++) {
                int m = m0 + wm + i * 16 + lg * 4 + r;
                out[(size_t)m * EMBED + n] = acc[i][j][r] + b;
            }
        }
    }
}

// ---------------- flash attention (swapped-QK^T, swizzled LDS, 2-phase) ----------------
// Qh: pre-scaled by QSCALE (log2 domain). Kh: [96][1024][64]. Vtg: [96][64][1024].
__global__ __launch_bounds__(256, 4) void attn_kernel(
        const short* __restrict__ Qh, const short* __restrict__ Kh,
        const short* __restrict__ Vtg, short* __restrict__ ctx) {
    __shared__ short Klds[2][64 * 64];   // [key][hd], 16B-chunk XOR-swizzled by key&7
    __shared__ short Vlds[2][64 * 64];   // [hd][key], 16B-chunk XOR-swizzled by hd&7
    __shared__ short Plds[4][16 * 64];   // per-wave P[q][k], swizzled by q&7

    const int bid = blockIdx.x;
    const int bh = bid % BH;             // XCD-affinity: all 16 q-blocks of a head share bid%8
    const int q0 = (bid / BH) * 64;
    const int t = threadIdx.x, l = t & 63, w = t >> 6;
    const int lr = l & 15, lg = l >> 4;
    const int pmask = lr & 7;
    const size_t headbase = (size_t)bh * NSEQ;

    bf16x8 aq0, aq1;
    {
        const short* qb = Qh + (headbase + q0 + w * 16 + lr) * HDIM + lg * 8;
        aq0 = *reinterpret_cast<const bf16x8*>(qb);
        aq1 = *reinterpret_cast<const bf16x8*>(qb + 32);
    }

    const int srow = t >> 3, sseg = t & 7;

    auto stage = [&](int bufb, int kt0) {
        #pragma unroll
        for (int p = 0; p < 2; p++) {
            int row = srow + p * 32;
            int sw = (sseg ^ (row & 7)) << 3;    // pre-swizzled global chunk (involution)
            GLD_LDS(Kh + (headbase + kt0 + row) * HDIM + sw,
                    &Klds[bufb][row * 64 + sseg * 8]);
            GLD_LDS(Vtg + (((size_t)(bh * HDIM + row)) << 10) + kt0 + sw,
                    &Vlds[bufb][row * 64 + sseg * 8]);
        }
    };

    f32x4 accc[4] = {};      // ctx[q = lg*4+r (within wave 16)][hd = ht*16+lr]
    float mrun = -1e30f, lrun = 0.f;   // per-lane stats for q = lr (log2 domain)

    stage(0, 0);
    __syncthreads();

    int cur = 0;
    for (int it = 0; it < NSEQ / 64; ++it) {
        if (it + 1 < NSEQ / 64) stage(cur ^ 1, (it + 1) * 64);

        // S^T[k][q] = K Q^T : lane holds s[kt][r] = S[q=lr][k = kt*16+lg*4+r]
        f32x4 s[4];
        const short* Kb = Klds[cur];
        __builtin_amdgcn_s_setprio(1);
        #pragma unroll
        for (int kt = 0; kt < 4; kt++) {
            const short* kb = Kb + (kt * 16 + lr) * 64;
            bf16x8 ak0 = *reinterpret_cast<const bf16x8*>(kb + ((lg ^ pmask) << 3));
            bf16x8 ak1 = *reinterpret_cast<const bf16x8*>(kb + (((lg + 4) ^ pmask) << 3));
            f32x4 z = {};
            z = MFMA32(ak0, aq0, z);
            z = MFMA32(ak1, aq1, z);
            s[kt] = z;
        }
        __builtin_amdgcn_s_setprio(0);

        // ---- online softmax, exp2 domain, tree reductions, defer-max (T13) ----
        float g0 = fmaxf(fmaxf(s[0][0], s[0][1]), fmaxf(s[0][2], s[0][3]));
        float g1 = fmaxf(fmaxf(s[1][0], s[1][1]), fmaxf(s[1][2], s[1][3]));
        float g2 = fmaxf(fmaxf(s[2][0], s[2][1]), fmaxf(s[2][2], s[2][3]));
        float g3 = fmaxf(fmaxf(s[3][0], s[3][1]), fmaxf(s[3][2], s[3][3]));
        float pm = fmaxf(fmaxf(g0, g1), fmaxf(g2, g3));
        pm = fmaxf(pm, __shfl_xor(pm, 16));
        pm = fmaxf(pm, __shfl_xor(pm, 32));
        if (!__all(pm - mrun <= 8.f)) {
            float mnew = fmaxf(mrun, pm);
            float alpha = fexp2(mrun - mnew);
            mrun = mnew;
            lrun *= alpha;
            #pragma unroll
            for (int r = 0; r < 4; r++) {
                float ar = __shfl(alpha, (lg << 4) | (lg * 4 + r));
                #pragma unroll
                for (int ht = 0; ht < 4; ht++) accc[ht][r] *= ar;
            }
        }
        #pragma unroll
        for (int kt = 0; kt < 4; kt++)
            #pragma unroll
            for (int r = 0; r < 4; r++)
                s[kt][r] = fexp2(s[kt][r] - mrun);
        float a0 = (s[0][0] + s[0][1]) + (s[0][2] + s[0][3]);
        float a1 = (s[1][0] + s[1][1]) + (s[1][2] + s[1][3]);
        float a2 = (s[2][0] + s[2][1]) + (s[2][2] + s[2][3]);
        float a3 = (s[3][0] + s[3][1]) + (s[3][2] + s[3][3]);
        float ts = (a0 + a1) + (a2 + a3);
        ts += __shfl_xor(ts, 16);
        ts += __shfl_xor(ts, 32);
        lrun += ts;

        // pack P -> per-wave LDS in A-operand layout P[q][k], swizzled, 8B writes
        short* pw = &Plds[w][0];
        #pragma unroll
        for (int kt = 0; kt < 4; kt++) {
            s16x4 pk;
            #pragma unroll
            for (int r = 0; r < 4; r++) pk[r] = f2bf(s[kt][r]);
            int chunk = kt * 2 + (lg >> 1);
            *reinterpret_cast<s16x4*>(pw + lr * 64 + (((chunk ^ pmask)) << 3) + ((lg & 1) << 2)) = pk;
        }

        // PV: D[q][hd] += P[q][k] V[k][hd]
        const short* Vb = Vlds[cur];
        #pragma unroll
        for (int kb = 0; kb < 2; kb++) {
            bf16x8 pa = *reinterpret_cast<const bf16x8*>(pw + lr * 64 + (((kb * 4 + lg) ^ pmask) << 3));
            __builtin_amdgcn_s_setprio(1);
            #pragma unroll
            for (int ht = 0; ht < 4; ht++) {
                const short* vb = Vb + (ht * 16 + lr) * 64 + (((kb * 4 + lg) ^ pmask) << 3);
                bf16x8 bv = *reinterpret_cast<const bf16x8*>(vb);
                accc[ht] = MFMA32(pa, bv, accc[ht]);
            }
            __builtin_amdgcn_s_setprio(0);
        }

        __syncthreads();
        cur ^= 1;
    }

    // epilogue: ctx[b, q, h*64 + ht*16 + lr] = acc / l(q),  q = q0 + w*16 + lg*4 + r
    int b = bh / HEADS, h = bh % HEADS;
    #pragma unroll
    for (int r = 0; r < 4; r++) {
        float linv = 1.f / __shfl(lrun, (lg << 4) | (lg * 4 + r));
        int q = q0 + w * 16 + lg * 4 + r;
        #pragma unroll
        for (int ht = 0; ht < 4; ht++)
            ctx[((size_t)b * NSEQ + q) * EMBED + h * HDIM + ht * 16 + lr] = f2bf(accc[ht][r] * linv);
    }
}

// ---------------- launch ----------------

extern "C" void kernel_launch(void* const* d_in, const int* in_sizes, int n_in,
                              void* d_out, int out_size, void* d_ws, size_t ws_size,
                              hipStream_t stream) {
    (void)in_sizes; (void)n_in; (void)out_size; (void)ws_size;
    const float* x  = (const float*)d_in[0];
    const float* Wq = (const float*)d_in[1];
    const float* bq = (const float*)d_in[2];
    const float* Wk = (const float*)d_in[3];
    const float* bk = (const float*)d_in[4];
    const float* Wv = (const float*)d_in[5];
    const float* bv = (const float*)d_in[6];
    const float* Wo = (const float*)d_in[7];
    const float* bo = (const float*)d_in[8];
    float* out = (float*)d_out;

    char* ws = (char*)d_ws;
    size_t off = 0;
    short* xb  = (short*)(ws + off); off += (size_t)MROWS * EMBED * 2;
    short* Wtq = (short*)(ws + off); off += (size_t)EMBED * EMBED * 2;   // ┐ contiguous:
    short* Wtk = (short*)(ws + off); off += (size_t)EMBED * EMBED * 2;   // │ Bt = Wtq is
    short* Wtv = (short*)(ws + off); off += (size_t)EMBED * EMBED * 2;   // ┘ [2304][768]
    short* Wto = (short*)(ws + off); off += (size_t)EMBED * EMBED * 2;
    short* Qh  = (short*)(ws + off); off += (size_t)BH * NSEQ * HDIM * 2;
    short* Kh  = (short*)(ws + off); off += (size_t)BH * NSEQ * HDIM * 2;
    short* Vtg = (short*)(ws + off); off += (size_t)BH * NSEQ * HDIM * 2;
    short* ctx = (short*)(ws + off); off += (size_t)MROWS * EMBED * 2;

    cvt_x_kernel<<<2048, 256, 0, stream>>>(x, xb, MROWS * EMBED);
    dim3 gt(EMBED / 32, EMBED / 32, 4);
    transpose_w_kernel<<<gt, 256, 0, stream>>>(Wq, Wk, Wv, Wo, Wtq, Wtk, Wtv, Wto);

    gemm_qkv_kernel<<<(MROWS / 128) * (2304 / 128), 256, 0, stream>>>(
        xb, Wtq, bq, bk, bv, Qh, Kh, Vtg);

    attn_kernel<<<BH * (NSEQ / 64), 256, 0, stream>>>(Qh, Kh, Vtg, ctx);

    dim3 go(MROWS / 128, EMBED / 128);
    gemm_out_kernel<<<go, 256, 0, stream>>>(ctx, Wto, bo, out);
}

// Round 4
// 126.887 us; speedup vs baseline: 1.8766x; 1.0495x over previous
//
#include <hip/hip_runtime.h>
#include <hip/hip_bf16.h>
#include <cstdint>
#include <cstddef>

#define EMBED 768
#define NSEQ 1024
#define BATCH 8
#define HEADS 12
#define HDIM 64
#define BH (BATCH*HEADS)      // 96
#define MROWS (BATCH*NSEQ)    // 8192

typedef __attribute__((ext_vector_type(8))) short bf16x8;
typedef __attribute__((ext_vector_type(4))) short s16x4;
typedef __attribute__((ext_vector_type(4))) float f32x4;

__device__ __forceinline__ short f2bf(float f) {
    __hip_bfloat16 h = __float2bfloat16(f);
    return __builtin_bit_cast(short, h);
}

__device__ __forceinline__ float fexp2(float x) {
#if __has_builtin(__builtin_amdgcn_exp2f)
    return __builtin_amdgcn_exp2f(x);
#else
    return exp2f(x);
#endif
}

#define GLD_LDS(g, l) __builtin_amdgcn_global_load_lds( \
    (const __attribute__((address_space(1))) void*)(g), \
    (__attribute__((address_space(3))) void*)(l), 16, 0, 0)

#define MFMA32(a, b, c) __builtin_amdgcn_mfma_f32_16x16x32_bf16((a), (b), (c), 0, 0, 0)

#define QSCALE 0.180336881f   /* (1/8) * log2(e): S computed directly in log2 domain */

// ---------------- conversion kernels ----------------

__global__ __launch_bounds__(256) void cvt_x_kernel(const float* __restrict__ x,
                                                    short* __restrict__ xb, int n) {
    int stride = gridDim.x * blockDim.x * 4;
    for (int i = (blockIdx.x * blockDim.x + threadIdx.x) * 4; i < n; i += stride) {
        float4 v = *reinterpret_cast<const float4*>(x + i);
        s16x4 o;
        o[0] = f2bf(v.x); o[1] = f2bf(v.y); o[2] = f2bf(v.z); o[3] = f2bf(v.w);
        *reinterpret_cast<s16x4*>(xb + i) = o;
    }
}

// W [768][768] fp32 (row = in/k, col = out/n)  ->  Wt [768][768] bf16 (row = n, col = k)
__global__ __launch_bounds__(256) void transpose_w_kernel(
        const float* __restrict__ W0, const float* __restrict__ W1,
        const float* __restrict__ W2, const float* __restrict__ W3,
        short* __restrict__ T0, short* __restrict__ T1,
        short* __restrict__ T2, short* __restrict__ T3) {
    const float* W; short* T;
    switch (blockIdx.z) {
        case 0: W = W0; T = T0; break;
        case 1: W = W1; T = T1; break;
        case 2: W = W2; T = T2; break;
        default: W = W3; T = T3; break;
    }
    __shared__ float tile[32][33];
    int n0 = blockIdx.x * 32, k0 = blockIdx.y * 32;
    int tx = threadIdx.x & 31, ty = threadIdx.x >> 5;   // ty: 0..7
    #pragma unroll
    for (int r = 0; r < 4; r++)
        tile[ty + r*8][tx] = W[(size_t)(k0 + ty + r*8) * EMBED + n0 + tx];
    __syncthreads();
    #pragma unroll
    for (int r = 0; r < 4; r++)
        T[(size_t)(n0 + ty + r*8) * EMBED + k0 + tx] = f2bf(tile[tx][ty + r*8]);
}

// ---------------- shared 128x128 K-loop ----------------
// SWAP=false: acc[i][j] = C fragment (regs = m axis).
// SWAP=true:  acc[i][j] = C^T fragment (regs = n axis) via mfma(B,A) = (AB)^T.
template<bool SWAP>
__device__ __forceinline__ void gemm_kloop(
        const short* __restrict__ A, const short* __restrict__ Bt,
        int m0, int n0, int t, short* Alds, short* Blds, f32x4 (*acc)[4]) {
    const int l = t & 63, w = t >> 6;
    const int wm = (w >> 1) * 64, wn = (w & 1) * 64;
    const int lr = l & 15, lg = l >> 4;
    const int arow = t >> 2, aseg = t & 3;

    for (int k0 = 0; k0 < EMBED; k0 += 32) {
        __syncthreads();
        #pragma unroll
        for (int p = 0; p < 2; ++p) {
            int row = arow + p * 64;
            GLD_LDS(A  + (size_t)(m0 + row) * EMBED + k0 + aseg * 8, Alds + row * 32 + aseg * 8);
            GLD_LDS(Bt + (size_t)(n0 + row) * EMBED + k0 + aseg * 8, Blds + row * 32 + aseg * 8);
        }
        __syncthreads();
        bf16x8 af[4], bfr[4];
        #pragma unroll
        for (int i = 0; i < 4; i++)
            af[i] = *reinterpret_cast<const bf16x8*>(Alds + (wm + i*16 + lr) * 32 + lg * 8);
        #pragma unroll
        for (int j = 0; j < 4; j++)
            bfr[j] = *reinterpret_cast<const bf16x8*>(Blds + (wn + j*16 + lr) * 32 + lg * 8);
        #pragma unroll
        for (int i = 0; i < 4; i++)
            #pragma unroll
            for (int j = 0; j < 4; j++) {
                if (SWAP) acc[i][j] = MFMA32(bfr[j], af[i], acc[i][j]);
                else      acc[i][j] = MFMA32(af[i], bfr[j], acc[i][j]);
            }
    }
}

// ---------------- fused QKV GEMM: [8192 x 768] @ [768 x 2304] ----------------
__global__ __launch_bounds__(256) void gemm_qkv_kernel(
        const short* __restrict__ A, const short* __restrict__ Bt,
        const float* __restrict__ bq, const float* __restrict__ bk,
        const float* __restrict__ bv,
        short* __restrict__ Qh, short* __restrict__ Kh, short* __restrict__ Vtg) {
    __shared__ short Alds[128 * 32];
    __shared__ short Blds[128 * 32];
    // XCD-bijective swizzle (1152 % 8 == 0), n-fastest inside each XCD chunk.
    const int id = blockIdx.x;
    const int flat = (id & 7) * 144 + (id >> 3);
    const int mi = flat / 18, ni = flat - mi * 18;
    const int m0 = mi * 128, n0 = ni * 128;

    const int t = threadIdx.x;
    const int l = t & 63, w = t >> 6;
    const int wm = (w >> 1) * 64, wn = (w & 1) * 64;
    const int lr = l & 15, lg = l >> 4;

    const int regb = n0 / 768;           // block-uniform (768 % 128 == 0)
    f32x4 acc[4][4] = {};

    if (regb < 2) {
        // Q/K: accumulate C^T so regs = hd axis -> packed 8B stores
        gemm_kloop<true>(A, Bt, m0, n0, t, Alds, Blds, acc);
        const float* bias = regb ? bk : bq;
        short* dst = regb ? Kh : Qh;
        const float scale = regb ? 1.0f : QSCALE;
        const int nbase = n0 - regb * 768;
        #pragma unroll
        for (int j = 0; j < 4; j++) {
            const int nf = nbase + wn + j * 16 + lg * 4;
            const float4 bl = *reinterpret_cast<const float4*>(bias + nf);
            const int h = nf >> 6, hd0 = nf & 63;
            #pragma unroll
            for (int i = 0; i < 4; i++) {
                const int m = m0 + wm + i * 16 + lr;
                const int bi = m >> 10, seq = m & 1023;
                s16x4 pk;
                pk[0] = f2bf((acc[i][j][0] + bl.x) * scale);
                pk[1] = f2bf((acc[i][j][1] + bl.y) * scale);
                pk[2] = f2bf((acc[i][j][2] + bl.z) * scale);
                pk[3] = f2bf((acc[i][j][3] + bl.w) * scale);
                *reinterpret_cast<s16x4*>(dst +
                    ((size_t)(bi * HEADS + h) * NSEQ + seq) * HDIM + hd0) = pk;
            }
        }
    } else {
        // V: normal orientation (regs = seq axis) -> packed stores into [B,H,64,N]
        gemm_kloop<false>(A, Bt, m0, n0, t, Alds, Blds, acc);
        #pragma unroll
        for (int j = 0; j < 4; j++) {
            const int nn = n0 + wn + j * 16 + lr - 1536;
            const int h = nn >> 6, hd = nn & 63;
            const float b = bv[nn];
            #pragma unroll
            for (int i = 0; i < 4; i++) {
                const int mbase = m0 + wm + i * 16 + lg * 4;
                const int bi = mbase >> 10, seq = mbase & 1023;
                s16x4 pk;
                #pragma unroll
                for (int r = 0; r < 4; r++) pk[r] = f2bf(acc[i][j][r] + b);
                *reinterpret_cast<s16x4*>(Vtg +
                    ((size_t)((bi * HEADS + h) * HDIM + hd)) * NSEQ + seq) = pk;
            }
        }
    }
}

// ---------------- output projection GEMM (C^T accumulation, float4 stores) ----------------
__global__ __launch_bounds__(256) void gemm_out_kernel(
        const short* __restrict__ A, const short* __restrict__ Bt,
        const float* __restrict__ bias, float* __restrict__ out) {
    __shared__ short Alds[128 * 32];
    __shared__ short Blds[128 * 32];
    const int m0 = blockIdx.x * 128;
    const int n0 = blockIdx.y * 128;
    const int t = threadIdx.x;
    const int l = t & 63, w = t >> 6;
    const int wm = (w >> 1) * 64, wn = (w & 1) * 64;
    const int lr = l & 15, lg = l >> 4;

    f32x4 acc[4][4] = {};
    gemm_kloop<true>(A, Bt, m0, n0, t, Alds, Blds, acc);

    #pragma unroll
    for (int j = 0; j < 4; j++) {
        const int nf = n0 + wn + j * 16 + lg * 4;
        const float4 bl = *reinterpret_cast<const float4*>(bias + nf);
        #pragma unroll
        for (int i = 0; i < 4; i++) {
            const int m = m0 + wm + i * 16 + lr;
            float4 o;
            o.x = acc[i][j][0] + bl.x;
            o.y = acc[i][j][1] + bl.y;
            o.z = acc[i][j][2] + bl.z;
            o.w = acc[i][j][3] + bl.w;
            *reinterpret_cast<float4*>(out + (size_t)m * EMBED + nf) = o;
        }
    }
}

// ---------------- flash attention: 2 q-tiles/wave, K/V-frag reuse ----------------
// Qh: pre-scaled by QSCALE (log2 domain). Kh: [96][1024][64]. Vtg: [96][64][1024].
__global__ __launch_bounds__(256, 3) void attn_kernel(
        const short* __restrict__ Qh, const short* __restrict__ Kh,
        const short* __restrict__ Vtg, short* __restrict__ ctx) {
    __shared__ short Klds[2][64 * 64];     // [key][hd], 16B-chunk XOR-swizzled by key&7
    __shared__ short Vlds[2][64 * 64];     // [hd][key], swizzled by hd&7
    __shared__ short Plds[4][2][16 * 64];  // per-wave, per-q-tile P[q][k], swizzled by q&7

    const int bid = blockIdx.x;
    const int bh = bid % BH;               // XCD affinity: q-blocks of a head share bid%8
    const int q0 = (bid / BH) * 128;
    const int t = threadIdx.x, l = t & 63, w = t >> 6;
    const int lr = l & 15, lg = l >> 4;
    const int pmask = lr & 7;
    const size_t headbase = (size_t)bh * NSEQ;

    // Q fragments for both q-tiles, registers for the whole kernel
    bf16x8 aq00, aq01, aq10, aq11;
    {
        const short* qb0 = Qh + (headbase + q0 + w * 16 + lr) * HDIM + lg * 8;
        aq00 = *reinterpret_cast<const bf16x8*>(qb0);
        aq01 = *reinterpret_cast<const bf16x8*>(qb0 + 32);
        const short* qb1 = qb0 + 64 * HDIM;
        aq10 = *reinterpret_cast<const bf16x8*>(qb1);
        aq11 = *reinterpret_cast<const bf16x8*>(qb1 + 32);
    }

    const int srow = t >> 3, sseg = t & 7;
    auto stage = [&](int bufb, int kt0) {
        #pragma unroll
        for (int p = 0; p < 2; p++) {
            int row = srow + p * 32;
            int sw = (sseg ^ (row & 7)) << 3;   // pre-swizzled global chunk (involution)
            GLD_LDS(Kh + (headbase + kt0 + row) * HDIM + sw,
                    &Klds[bufb][row * 64 + sseg * 8]);
            GLD_LDS(Vtg + (((size_t)(bh * HDIM + row)) << 10) + kt0 + sw,
                    &Vlds[bufb][row * 64 + sseg * 8]);
        }
    };

    f32x4 acc0[4] = {}, acc1[4] = {};
    float mrun0 = -1e30f, lrun0 = 0.f, mrun1 = -1e30f, lrun1 = 0.f;

    // online softmax in log2 domain; tree reductions; defer-max (T13)
    auto softmax = [&](f32x4* s, float& mrun, float& lrun, f32x4* acc) {
        float g0 = fmaxf(fmaxf(s[0][0], s[0][1]), fmaxf(s[0][2], s[0][3]));
        float g1 = fmaxf(fmaxf(s[1][0], s[1][1]), fmaxf(s[1][2], s[1][3]));
        float g2 = fmaxf(fmaxf(s[2][0], s[2][1]), fmaxf(s[2][2], s[2][3]));
        float g3 = fmaxf(fmaxf(s[3][0], s[3][1]), fmaxf(s[3][2], s[3][3]));
        float pm = fmaxf(fmaxf(g0, g1), fmaxf(g2, g3));
        pm = fmaxf(pm, __shfl_xor(pm, 16));
        pm = fmaxf(pm, __shfl_xor(pm, 32));
        if (!__all(pm - mrun <= 8.f)) {
            float mnew = fmaxf(mrun, pm);
            float alpha = fexp2(mrun - mnew);
            mrun = mnew;
            lrun *= alpha;
            #pragma unroll
            for (int r = 0; r < 4; r++) {
                float ar = __shfl(alpha, (lg << 4) | (lg * 4 + r));
                #pragma unroll
                for (int ht = 0; ht < 4; ht++) acc[ht][r] *= ar;
            }
        }
        #pragma unroll
        for (int kt = 0; kt < 4; kt++)
            #pragma unroll
            for (int r = 0; r < 4; r++)
                s[kt][r] = fexp2(s[kt][r] - mrun);
        float a0 = (s[0][0] + s[0][1]) + (s[0][2] + s[0][3]);
        float a1 = (s[1][0] + s[1][1]) + (s[1][2] + s[1][3]);
        float a2 = (s[2][0] + s[2][1]) + (s[2][2] + s[2][3]);
        float a3 = (s[3][0] + s[3][1]) + (s[3][2] + s[3][3]);
        float ts = (a0 + a1) + (a2 + a3);
        ts += __shfl_xor(ts, 16);
        ts += __shfl_xor(ts, 32);
        lrun += ts;
    };

    stage(0, 0);
    __syncthreads();

    int cur = 0;
    for (int it = 0; it < NSEQ / 64; ++it) {
        if (it + 1 < NSEQ / 64) stage(cur ^ 1, (it + 1) * 64);

        // S^T = K Q^T for both q-tiles; K-fragments loaded once, used twice
        f32x4 s0[4], s1[4];
        const short* Kb = Klds[cur];
        __builtin_amdgcn_s_setprio(1);
        #pragma unroll
        for (int kt = 0; kt < 4; kt++) {
            const short* kb = Kb + (kt * 16 + lr) * 64;
            bf16x8 ak0 = *reinterpret_cast<const bf16x8*>(kb + ((lg ^ pmask) << 3));
            bf16x8 ak1 = *reinterpret_cast<const bf16x8*>(kb + (((lg + 4) ^ pmask) << 3));
            f32x4 z0 = {}, z1 = {};
            z0 = MFMA32(ak0, aq00, z0);
            z1 = MFMA32(ak0, aq10, z1);
            z0 = MFMA32(ak1, aq01, z0);
            z1 = MFMA32(ak1, aq11, z1);
            s0[kt] = z0; s1[kt] = z1;
        }
        __builtin_amdgcn_s_setprio(0);

        softmax(s0, mrun0, lrun0, acc0);
        softmax(s1, mrun1, lrun1, acc1);

        // pack P -> per-wave per-tile LDS, A-operand layout, swizzled 8B writes
        short* pw0 = &Plds[w][0][0];
        short* pw1 = &Plds[w][1][0];
        #pragma unroll
        for (int kt = 0; kt < 4; kt++) {
            s16x4 pk0, pk1;
            #pragma unroll
            for (int r = 0; r < 4; r++) { pk0[r] = f2bf(s0[kt][r]); pk1[r] = f2bf(s1[kt][r]); }
            int chunk = kt * 2 + (lg >> 1);
            int off = lr * 64 + ((chunk ^ pmask) << 3) + ((lg & 1) << 2);
            *reinterpret_cast<s16x4*>(pw0 + off) = pk0;
            *reinterpret_cast<s16x4*>(pw1 + off) = pk1;
        }

        // PV: V-fragments loaded once, used for both q-tiles
        const short* Vb = Vlds[cur];
        #pragma unroll
        for (int kb = 0; kb < 2; kb++) {
            int poff = lr * 64 + (((kb * 4 + lg) ^ pmask) << 3);
            bf16x8 pa0 = *reinterpret_cast<const bf16x8*>(pw0 + poff);
            bf16x8 pa1 = *reinterpret_cast<const bf16x8*>(pw1 + poff);
            __builtin_amdgcn_s_setprio(1);
            #pragma unroll
            for (int ht = 0; ht < 4; ht++) {
                const short* vb = Vb + (ht * 16 + lr) * 64 + (((kb * 4 + lg) ^ pmask) << 3);
                bf16x8 bv = *reinterpret_cast<const bf16x8*>(vb);
                acc0[ht] = MFMA32(pa0, bv, acc0[ht]);
                acc1[ht] = MFMA32(pa1, bv, acc1[ht]);
            }
            __builtin_amdgcn_s_setprio(0);
        }

        __syncthreads();
        cur ^= 1;
    }

    // epilogue
    int b = bh / HEADS, h = bh % HEADS;
    #pragma unroll
    for (int r = 0; r < 4; r++) {
        int src = (lg << 4) | (lg * 4 + r);
        float linv0 = 1.f / __shfl(lrun0, src);
        float linv1 = 1.f / __shfl(lrun1, src);
        int q = q0 + w * 16 + lg * 4 + r;
        #pragma unroll
        for (int ht = 0; ht < 4; ht++) {
            ctx[((size_t)b * NSEQ + q) * EMBED + h * HDIM + ht * 16 + lr] =
                f2bf(acc0[ht][r] * linv0);
            ctx[((size_t)b * NSEQ + q + 64) * EMBED + h * HDIM + ht * 16 + lr] =
                f2bf(acc1[ht][r] * linv1);
        }
    }
}

// ---------------- launch ----------------

extern "C" void kernel_launch(void* const* d_in, const int* in_sizes, int n_in,
                              void* d_out, int out_size, void* d_ws, size_t ws_size,
                              hipStream_t stream) {
    (void)in_sizes; (void)n_in; (void)out_size; (void)ws_size;
    const float* x  = (const float*)d_in[0];
    const float* Wq = (const float*)d_in[1];
    const float* bq = (const float*)d_in[2];
    const float* Wk = (const float*)d_in[3];
    const float* bk = (const float*)d_in[4];
    const float* Wv = (const float*)d_in[5];
    const float* bv = (const float*)d_in[6];
    const float* Wo = (const float*)d_in[7];
    const float* bo = (const float*)d_in[8];
    float* out = (float*)d_out;

    char* ws = (char*)d_ws;
    size_t off = 0;
    short* xb  = (short*)(ws + off); off += (size_t)MROWS * EMBED * 2;
    short* Wtq = (short*)(ws + off); off += (size_t)EMBED * EMBED * 2;   // ┐ contiguous:
    short* Wtk = (short*)(ws + off); off += (size_t)EMBED * EMBED * 2;   // │ Bt = Wtq is
    short* Wtv = (short*)(ws + off); off += (size_t)EMBED * EMBED * 2;   // ┘ [2304][768]
    short* Wto = (short*)(ws + off); off += (size_t)EMBED * EMBED * 2;
    short* Qh  = (short*)(ws + off); off += (size_t)BH * NSEQ * HDIM * 2;
    short* Kh  = (short*)(ws + off); off += (size_t)BH * NSEQ * HDIM * 2;
    short* Vtg = (short*)(ws + off); off += (size_t)BH * NSEQ * HDIM * 2;
    short* ctx = (short*)(ws + off); off += (size_t)MROWS * EMBED * 2;

    cvt_x_kernel<<<2048, 256, 0, stream>>>(x, xb, MROWS * EMBED);
    dim3 gt(EMBED / 32, EMBED / 32, 4);
    transpose_w_kernel<<<gt, 256, 0, stream>>>(Wq, Wk, Wv, Wo, Wtq, Wtk, Wtv, Wto);

    gemm_qkv_kernel<<<(MROWS / 128) * (2304 / 128), 256, 0, stream>>>(
        xb, Wtq, bq, bk, bv, Qh, Kh, Vtg);

    attn_kernel<<<BH * (NSEQ / 128), 256, 0, stream>>>(Qh, Kh, Vtg, ctx);

    dim3 go(MROWS / 128, EMBED / 128);
    gemm_out_kernel<<<go, 256, 0, stream>>>(ctx, Wto, bo, out);
}

// Round 5
// 122.630 us; speedup vs baseline: 1.9417x; 1.0347x over previous
//
#include <hip/hip_runtime.h>
#include <hip/hip_bf16.h>
#include <cstdint>
#include <cstddef>

#define EMBED 768
#define NSEQ 1024
#define BATCH 8
#define HEADS 12
#define HDIM 64
#define BH (BATCH*HEADS)      // 96
#define MROWS (BATCH*NSEQ)    // 8192
#define CVT_BLOCKS 2048

typedef __attribute__((ext_vector_type(8))) short bf16x8;
typedef __attribute__((ext_vector_type(4))) short s16x4;
typedef __attribute__((ext_vector_type(4))) float f32x4;

__device__ __forceinline__ short f2bf(float f) {
    __hip_bfloat16 h = __float2bfloat16(f);
    return __builtin_bit_cast(short, h);
}

__device__ __forceinline__ float fexp2(float x) {
#if __has_builtin(__builtin_amdgcn_exp2f)
    return __builtin_amdgcn_exp2f(x);
#else
    return exp2f(x);
#endif
}

#define GLD_LDS(g, l) __builtin_amdgcn_global_load_lds( \
    (const __attribute__((address_space(1))) void*)(g), \
    (__attribute__((address_space(3))) void*)(l), 16, 0, 0)

#define MFMA32(a, b, c) __builtin_amdgcn_mfma_f32_16x16x32_bf16((a), (b), (c), 0, 0, 0)

#define QSCALE 0.180336881f   /* (1/8) * log2(e): S computed directly in log2 domain */

// ---------------- fused prep: x->bf16 cast  +  4x W transpose ----------------
__global__ __launch_bounds__(256) void prep_kernel(
        const float* __restrict__ x, short* __restrict__ xb, int n,
        const float* __restrict__ W0, const float* __restrict__ W1,
        const float* __restrict__ W2, const float* __restrict__ W3,
        short* __restrict__ T0, short* __restrict__ T1,
        short* __restrict__ T2, short* __restrict__ T3) {
    __shared__ float tile[32][33];
    const int bid = blockIdx.x;
    if (bid < CVT_BLOCKS) {
        int stride = CVT_BLOCKS * 256 * 4;
        for (int i = (bid * 256 + threadIdx.x) * 4; i < n; i += stride) {
            float4 v = *reinterpret_cast<const float4*>(x + i);
            s16x4 o;
            o[0] = f2bf(v.x); o[1] = f2bf(v.y); o[2] = f2bf(v.z); o[3] = f2bf(v.w);
            *reinterpret_cast<s16x4*>(xb + i) = o;
        }
    } else {
        const int idx = bid - CVT_BLOCKS;          // 0..2303
        const int gz = idx / 576, rem = idx % 576;
        const int gx = rem % 24, gy = rem / 24;
        const float* W; short* T;
        switch (gz) {
            case 0: W = W0; T = T0; break;
            case 1: W = W1; T = T1; break;
            case 2: W = W2; T = T2; break;
            default: W = W3; T = T3; break;
        }
        int n0 = gx * 32, k0 = gy * 32;
        int tx = threadIdx.x & 31, ty = threadIdx.x >> 5;   // ty: 0..7
        #pragma unroll
        for (int r = 0; r < 4; r++)
            tile[ty + r*8][tx] = W[(size_t)(k0 + ty + r*8) * EMBED + n0 + tx];
        __syncthreads();
        #pragma unroll
        for (int r = 0; r < 4; r++)
            T[(size_t)(n0 + ty + r*8) * EMBED + k0 + tx] = f2bf(tile[tx][ty + r*8]);
    }
}

// ---------------- shared 128x128 K-loop: 2-phase double-buffered (T3-min) ----------------
// SWAP=false: acc[i][j] = C fragment (regs = m axis).
// SWAP=true:  acc[i][j] = C^T fragment (regs = n axis) via mfma(B,A) = (AB)^T.
// Single barrier per K-iter; STAGE(t+1) issued before compute(t); the implicit
// vmcnt(0) drain in __syncthreads lands after a full compute phase.
template<bool SWAP>
__device__ __forceinline__ void gemm_kloop(
        const short* __restrict__ A, const short* __restrict__ Bt,
        int m0, int n0, int t, short* Alds, short* Blds, f32x4 (*acc)[4]) {
    const int l = t & 63, w = t >> 6;
    const int wm = (w >> 1) * 64, wn = (w & 1) * 64;
    const int lr = l & 15, lg = l >> 4;
    const int arow = t >> 2, aseg = t & 3;

    auto stage = [&](int buf, int k0) {
        #pragma unroll
        for (int p = 0; p < 2; ++p) {
            int row = arow + p * 64;
            GLD_LDS(A  + (size_t)(m0 + row) * EMBED + k0 + aseg * 8,
                    Alds + buf * 4096 + row * 32 + aseg * 8);
            GLD_LDS(Bt + (size_t)(n0 + row) * EMBED + k0 + aseg * 8,
                    Blds + buf * 4096 + row * 32 + aseg * 8);
        }
    };

    stage(0, 0);
    __syncthreads();
    int cur = 0;
    for (int kn = 32; kn <= EMBED; kn += 32) {    // compute tile (kn-32), stage tile kn
        if (kn < EMBED) stage(cur ^ 1, kn);
        const short* Ab = Alds + cur * 4096;
        const short* Bb = Blds + cur * 4096;
        bf16x8 af[4], bfr[4];
        #pragma unroll
        for (int i = 0; i < 4; i++)
            af[i] = *reinterpret_cast<const bf16x8*>(Ab + (wm + i*16 + lr) * 32 + lg * 8);
        #pragma unroll
        for (int j = 0; j < 4; j++)
            bfr[j] = *reinterpret_cast<const bf16x8*>(Bb + (wn + j*16 + lr) * 32 + lg * 8);
        #pragma unroll
        for (int i = 0; i < 4; i++)
            #pragma unroll
            for (int j = 0; j < 4; j++) {
                if (SWAP) acc[i][j] = MFMA32(bfr[j], af[i], acc[i][j]);
                else      acc[i][j] = MFMA32(af[i], bfr[j], acc[i][j]);
            }
        __syncthreads();
        cur ^= 1;
    }
}

// ---------------- fused QKV GEMM: [8192 x 768] @ [768 x 2304] ----------------
__global__ __launch_bounds__(256) void gemm_qkv_kernel(
        const short* __restrict__ A, const short* __restrict__ Bt,
        const float* __restrict__ bq, const float* __restrict__ bk,
        const float* __restrict__ bv,
        short* __restrict__ Qh, short* __restrict__ Kh, short* __restrict__ Vtg) {
    __shared__ short Alds[2 * 128 * 32];
    __shared__ short Blds[2 * 128 * 32];
    // XCD-bijective swizzle (1152 % 8 == 0), n-fastest inside each XCD chunk.
    const int id = blockIdx.x;
    const int flat = (id & 7) * 144 + (id >> 3);
    const int mi = flat / 18, ni = flat - mi * 18;
    const int m0 = mi * 128, n0 = ni * 128;

    const int t = threadIdx.x;
    const int l = t & 63, w = t >> 6;
    const int wm = (w >> 1) * 64, wn = (w & 1) * 64;
    const int lr = l & 15, lg = l >> 4;

    const int regb = n0 / 768;           // block-uniform (768 % 128 == 0)
    f32x4 acc[4][4] = {};

    if (regb < 2) {
        // Q/K: accumulate C^T so regs = hd axis -> packed 8B stores
        gemm_kloop<true>(A, Bt, m0, n0, t, Alds, Blds, acc);
        const float* bias = regb ? bk : bq;
        short* dst = regb ? Kh : Qh;
        const float scale = regb ? 1.0f : QSCALE;
        const int nbase = n0 - regb * 768;
        #pragma unroll
        for (int j = 0; j < 4; j++) {
            const int nf = nbase + wn + j * 16 + lg * 4;
            const float4 bl = *reinterpret_cast<const float4*>(bias + nf);
            const int h = nf >> 6, hd0 = nf & 63;
            #pragma unroll
            for (int i = 0; i < 4; i++) {
                const int m = m0 + wm + i * 16 + lr;
                const int bi = m >> 10, seq = m & 1023;
                s16x4 pk;
                pk[0] = f2bf((acc[i][j][0] + bl.x) * scale);
                pk[1] = f2bf((acc[i][j][1] + bl.y) * scale);
                pk[2] = f2bf((acc[i][j][2] + bl.z) * scale);
                pk[3] = f2bf((acc[i][j][3] + bl.w) * scale);
                *reinterpret_cast<s16x4*>(dst +
                    ((size_t)(bi * HEADS + h) * NSEQ + seq) * HDIM + hd0) = pk;
            }
        }
    } else {
        // V: normal orientation (regs = seq axis) -> packed stores into [B,H,64,N]
        gemm_kloop<false>(A, Bt, m0, n0, t, Alds, Blds, acc);
        #pragma unroll
        for (int j = 0; j < 4; j++) {
            const int nn = n0 + wn + j * 16 + lr - 1536;
            const int h = nn >> 6, hd = nn & 63;
            const float b = bv[nn];
            #pragma unroll
            for (int i = 0; i < 4; i++) {
                const int mbase = m0 + wm + i * 16 + lg * 4;
                const int bi = mbase >> 10, seq = mbase & 1023;
                s16x4 pk;
                #pragma unroll
                for (int r = 0; r < 4; r++) pk[r] = f2bf(acc[i][j][r] + b);
                *reinterpret_cast<s16x4*>(Vtg +
                    ((size_t)((bi * HEADS + h) * HDIM + hd)) * NSEQ + seq) = pk;
            }
        }
    }
}

// ---------------- output projection GEMM (C^T accumulation, float4 stores) ----------------
__global__ __launch_bounds__(256) void gemm_out_kernel(
        const short* __restrict__ A, const short* __restrict__ Bt,
        const float* __restrict__ bias, float* __restrict__ out) {
    __shared__ short Alds[2 * 128 * 32];
    __shared__ short Blds[2 * 128 * 32];
    const int m0 = blockIdx.x * 128;
    const int n0 = blockIdx.y * 128;
    const int t = threadIdx.x;
    const int l = t & 63, w = t >> 6;
    const int wm = (w >> 1) * 64, wn = (w & 1) * 64;
    const int lr = l & 15, lg = l >> 4;

    f32x4 acc[4][4] = {};
    gemm_kloop<true>(A, Bt, m0, n0, t, Alds, Blds, acc);

    #pragma unroll
    for (int j = 0; j < 4; j++) {
        const int nf = n0 + wn + j * 16 + lg * 4;
        const float4 bl = *reinterpret_cast<const float4*>(bias + nf);
        #pragma unroll
        for (int i = 0; i < 4; i++) {
            const int m = m0 + wm + i * 16 + lr;
            float4 o;
            o.x = acc[i][j][0] + bl.x;
            o.y = acc[i][j][1] + bl.y;
            o.z = acc[i][j][2] + bl.z;
            o.w = acc[i][j][3] + bl.w;
            *reinterpret_cast<float4*>(out + (size_t)m * EMBED + nf) = o;
        }
    }
}

// ---------------- flash attention: 2 q-tiles/wave, K/V-frag reuse ----------------
// Qh: pre-scaled by QSCALE (log2 domain). Kh: [96][1024][64]. Vtg: [96][64][1024].
__global__ __launch_bounds__(256, 3) void attn_kernel(
        const short* __restrict__ Qh, const short* __restrict__ Kh,
        const short* __restrict__ Vtg, short* __restrict__ ctx) {
    __shared__ short Klds[2][64 * 64];     // [key][hd], 16B-chunk XOR-swizzled by key&7
    __shared__ short Vlds[2][64 * 64];     // [hd][key], swizzled by hd&7
    __shared__ short Plds[4][2][16 * 64];  // per-wave, per-q-tile P[q][k], swizzled by q&7

    const int bid = blockIdx.x;
    const int bh = bid % BH;               // XCD affinity: q-blocks of a head share bid%8
    const int q0 = (bid / BH) * 128;
    const int t = threadIdx.x, l = t & 63, w = t >> 6;
    const int lr = l & 15, lg = l >> 4;
    const int pmask = lr & 7;
    const size_t headbase = (size_t)bh * NSEQ;

    // Q fragments for both q-tiles, registers for the whole kernel
    bf16x8 aq00, aq01, aq10, aq11;
    {
        const short* qb0 = Qh + (headbase + q0 + w * 16 + lr) * HDIM + lg * 8;
        aq00 = *reinterpret_cast<const bf16x8*>(qb0);
        aq01 = *reinterpret_cast<const bf16x8*>(qb0 + 32);
        const short* qb1 = qb0 + 64 * HDIM;
        aq10 = *reinterpret_cast<const bf16x8*>(qb1);
        aq11 = *reinterpret_cast<const bf16x8*>(qb1 + 32);
    }

    const int srow = t >> 3, sseg = t & 7;
    auto stage = [&](int bufb, int kt0) {
        #pragma unroll
        for (int p = 0; p < 2; p++) {
            int row = srow + p * 32;
            int sw = (sseg ^ (row & 7)) << 3;   // pre-swizzled global chunk (involution)
            GLD_LDS(Kh + (headbase + kt0 + row) * HDIM + sw,
                    &Klds[bufb][row * 64 + sseg * 8]);
            GLD_LDS(Vtg + (((size_t)(bh * HDIM + row)) << 10) + kt0 + sw,
                    &Vlds[bufb][row * 64 + sseg * 8]);
        }
    };

    f32x4 acc0[4] = {}, acc1[4] = {};
    float mrun0 = -1e30f, lrun0 = 0.f, mrun1 = -1e30f, lrun1 = 0.f;

    // online softmax in log2 domain; tree reductions; defer-max (T13)
    auto softmax = [&](f32x4* s, float& mrun, float& lrun, f32x4* acc) {
        float g0 = fmaxf(fmaxf(s[0][0], s[0][1]), fmaxf(s[0][2], s[0][3]));
        float g1 = fmaxf(fmaxf(s[1][0], s[1][1]), fmaxf(s[1][2], s[1][3]));
        float g2 = fmaxf(fmaxf(s[2][0], s[2][1]), fmaxf(s[2][2], s[2][3]));
        float g3 = fmaxf(fmaxf(s[3][0], s[3][1]), fmaxf(s[3][2], s[3][3]));
        float pm = fmaxf(fmaxf(g0, g1), fmaxf(g2, g3));
        pm = fmaxf(pm, __shfl_xor(pm, 16));
        pm = fmaxf(pm, __shfl_xor(pm, 32));
        if (!__all(pm - mrun <= 8.f)) {
            float mnew = fmaxf(mrun, pm);
            float alpha = fexp2(mrun - mnew);
            mrun = mnew;
            lrun *= alpha;
            #pragma unroll
            for (int r = 0; r < 4; r++) {
                float ar = __shfl(alpha, (lg << 4) | (lg * 4 + r));
                #pragma unroll
                for (int ht = 0; ht < 4; ht++) acc[ht][r] *= ar;
            }
        }
        #pragma unroll
        for (int kt = 0; kt < 4; kt++)
            #pragma unroll
            for (int r = 0; r < 4; r++)
                s[kt][r] = fexp2(s[kt][r] - mrun);
        float a0 = (s[0][0] + s[0][1]) + (s[0][2] + s[0][3]);
        float a1 = (s[1][0] + s[1][1]) + (s[1][2] + s[1][3]);
        float a2 = (s[2][0] + s[2][1]) + (s[2][2] + s[2][3]);
        float a3 = (s[3][0] + s[3][1]) + (s[3][2] + s[3][3]);
        float ts = (a0 + a1) + (a2 + a3);
        ts += __shfl_xor(ts, 16);
        ts += __shfl_xor(ts, 32);
        lrun += ts;
    };

    stage(0, 0);
    __syncthreads();

    int cur = 0;
    for (int it = 0; it < NSEQ / 64; ++it) {
        if (it + 1 < NSEQ / 64) stage(cur ^ 1, (it + 1) * 64);

        // S^T = K Q^T for both q-tiles; K-fragments loaded once, used twice
        f32x4 s0[4], s1[4];
        const short* Kb = Klds[cur];
        __builtin_amdgcn_s_setprio(1);
        #pragma unroll
        for (int kt = 0; kt < 4; kt++) {
            const short* kb = Kb + (kt * 16 + lr) * 64;
            bf16x8 ak0 = *reinterpret_cast<const bf16x8*>(kb + ((lg ^ pmask) << 3));
            bf16x8 ak1 = *reinterpret_cast<const bf16x8*>(kb + (((lg + 4) ^ pmask) << 3));
            f32x4 z0 = {}, z1 = {};
            z0 = MFMA32(ak0, aq00, z0);
            z1 = MFMA32(ak0, aq10, z1);
            z0 = MFMA32(ak1, aq01, z0);
            z1 = MFMA32(ak1, aq11, z1);
            s0[kt] = z0; s1[kt] = z1;
        }
        __builtin_amdgcn_s_setprio(0);

        softmax(s0, mrun0, lrun0, acc0);
        softmax(s1, mrun1, lrun1, acc1);

        // pack P -> per-wave per-tile LDS, A-operand layout, swizzled 8B writes
        short* pw0 = &Plds[w][0][0];
        short* pw1 = &Plds[w][1][0];
        #pragma unroll
        for (int kt = 0; kt < 4; kt++) {
            s16x4 pk0, pk1;
            #pragma unroll
            for (int r = 0; r < 4; r++) { pk0[r] = f2bf(s0[kt][r]); pk1[r] = f2bf(s1[kt][r]); }
            int chunk = kt * 2 + (lg >> 1);
            int off = lr * 64 + ((chunk ^ pmask) << 3) + ((lg & 1) << 2);
            *reinterpret_cast<s16x4*>(pw0 + off) = pk0;
            *reinterpret_cast<s16x4*>(pw1 + off) = pk1;
        }

        // PV: V-fragments loaded once, used for both q-tiles
        const short* Vb = Vlds[cur];
        #pragma unroll
        for (int kb = 0; kb < 2; kb++) {
            int poff = lr * 64 + (((kb * 4 + lg) ^ pmask) << 3);
            bf16x8 pa0 = *reinterpret_cast<const bf16x8*>(pw0 + poff);
            bf16x8 pa1 = *reinterpret_cast<const bf16x8*>(pw1 + poff);
            __builtin_amdgcn_s_setprio(1);
            #pragma unroll
            for (int ht = 0; ht < 4; ht++) {
                const short* vb = Vb + (ht * 16 + lr) * 64 + (((kb * 4 + lg) ^ pmask) << 3);
                bf16x8 bv = *reinterpret_cast<const bf16x8*>(vb);
                acc0[ht] = MFMA32(pa0, bv, acc0[ht]);
                acc1[ht] = MFMA32(pa1, bv, acc1[ht]);
            }
            __builtin_amdgcn_s_setprio(0);
        }

        __syncthreads();
        cur ^= 1;
    }

    // epilogue
    int b = bh / HEADS, h = bh % HEADS;
    #pragma unroll
    for (int r = 0; r < 4; r++) {
        int src = (lg << 4) | (lg * 4 + r);
        float linv0 = 1.f / __shfl(lrun0, src);
        float linv1 = 1.f / __shfl(lrun1, src);
        int q = q0 + w * 16 + lg * 4 + r;
        #pragma unroll
        for (int ht = 0; ht < 4; ht++) {
            ctx[((size_t)b * NSEQ + q) * EMBED + h * HDIM + ht * 16 + lr] =
                f2bf(acc0[ht][r] * linv0);
            ctx[((size_t)b * NSEQ + q + 64) * EMBED + h * HDIM + ht * 16 + lr] =
                f2bf(acc1[ht][r] * linv1);
        }
    }
}

// ---------------- launch ----------------

extern "C" void kernel_launch(void* const* d_in, const int* in_sizes, int n_in,
                              void* d_out, int out_size, void* d_ws, size_t ws_size,
                              hipStream_t stream) {
    (void)in_sizes; (void)n_in; (void)out_size; (void)ws_size;
    const float* x  = (const float*)d_in[0];
    const float* Wq = (const float*)d_in[1];
    const float* bq = (const float*)d_in[2];
    const float* Wk = (const float*)d_in[3];
    const float* bk = (const float*)d_in[4];
    const float* Wv = (const float*)d_in[5];
    const float* bv = (const float*)d_in[6];
    const float* Wo = (const float*)d_in[7];
    const float* bo = (const float*)d_in[8];
    float* out = (float*)d_out;

    char* ws = (char*)d_ws;
    size_t off = 0;
    short* xb  = (short*)(ws + off); off += (size_t)MROWS * EMBED * 2;
    short* Wtq = (short*)(ws + off); off += (size_t)EMBED * EMBED * 2;   // ┐ contiguous:
    short* Wtk = (short*)(ws + off); off += (size_t)EMBED * EMBED * 2;   // │ Bt = Wtq is
    short* Wtv = (short*)(ws + off); off += (size_t)EMBED * EMBED * 2;   // ┘ [2304][768]
    short* Wto = (short*)(ws + off); off += (size_t)EMBED * EMBED * 2;
    short* Qh  = (short*)(ws + off); off += (size_t)BH * NSEQ * HDIM * 2;
    short* Kh  = (short*)(ws + off); off += (size_t)BH * NSEQ * HDIM * 2;
    short* Vtg = (short*)(ws + off); off += (size_t)BH * NSEQ * HDIM * 2;
    short* ctx = (short*)(ws + off); off += (size_t)MROWS * EMBED * 2;

    prep_kernel<<<CVT_BLOCKS + 2304, 256, 0, stream>>>(
        x, xb, MROWS * EMBED, Wq, Wk, Wv, Wo, Wtq, Wtk, Wtv, Wto);

    gemm_qkv_kernel<<<(MROWS / 128) * (2304 / 128), 256, 0, stream>>>(
        xb, Wtq, bq, bk, bv, Qh, Kh, Vtg);

    attn_kernel<<<BH * (NSEQ / 128), 256, 0, stream>>>(Qh, Kh, Vtg, ctx);

    dim3 go(MROWS / 128, EMBED / 128);
    gemm_out_kernel<<<go, 256, 0, stream>>>(ctx, Wto, bo, out);
}

// Round 6
// 122.534 us; speedup vs baseline: 1.9433x; 1.0008x over previous
//
#include <hip/hip_runtime.h>
#include <hip/hip_bf16.h>
#include <cstdint>
#include <cstddef>

#define EMBED 768
#define NSEQ 1024
#define BATCH 8
#define HEADS 12
#define HDIM 64
#define BH (BATCH*HEADS)      // 96
#define MROWS (BATCH*NSEQ)    // 8192
#define CVT_BLOCKS 2048
#define NKI (EMBED/32)        // 24 K-iters

typedef __attribute__((ext_vector_type(8))) short bf16x8;
typedef __attribute__((ext_vector_type(4))) short s16x4;
typedef __attribute__((ext_vector_type(4))) float f32x4;

__device__ __forceinline__ short f2bf(float f) {
    __hip_bfloat16 h = __float2bfloat16(f);
    return __builtin_bit_cast(short, h);
}

__device__ __forceinline__ float fexp2(float x) {
#if __has_builtin(__builtin_amdgcn_exp2f)
    return __builtin_amdgcn_exp2f(x);
#else
    return exp2f(x);
#endif
}

#define GLD_LDS(g, l) __builtin_amdgcn_global_load_lds( \
    (const __attribute__((address_space(1))) void*)(g), \
    (__attribute__((address_space(3))) void*)(l), 16, 0, 0)

#define MFMA32(a, b, c) __builtin_amdgcn_mfma_f32_16x16x32_bf16((a), (b), (c), 0, 0, 0)

#define QSCALE 0.180336881f   /* (1/8) * log2(e): S computed directly in log2 domain */

// ---------------- fused prep: x->bf16 cast  +  4x W transpose ----------------
__global__ __launch_bounds__(256) void prep_kernel(
        const float* __restrict__ x, short* __restrict__ xb, int n,
        const float* __restrict__ W0, const float* __restrict__ W1,
        const float* __restrict__ W2, const float* __restrict__ W3,
        short* __restrict__ T0, short* __restrict__ T1,
        short* __restrict__ T2, short* __restrict__ T3) {
    __shared__ float tile[32][33];
    const int bid = blockIdx.x;
    if (bid < CVT_BLOCKS) {
        int stride = CVT_BLOCKS * 256 * 4;
        for (int i = (bid * 256 + threadIdx.x) * 4; i < n; i += stride) {
            float4 v = *reinterpret_cast<const float4*>(x + i);
            s16x4 o;
            o[0] = f2bf(v.x); o[1] = f2bf(v.y); o[2] = f2bf(v.z); o[3] = f2bf(v.w);
            *reinterpret_cast<s16x4*>(xb + i) = o;
        }
    } else {
        const int idx = bid - CVT_BLOCKS;          // 0..2303
        const int gz = idx / 576, rem = idx % 576;
        const int gx = rem % 24, gy = rem / 24;
        const float* W; short* T;
        switch (gz) {
            case 0: W = W0; T = T0; break;
            case 1: W = W1; T = T1; break;
            case 2: W = W2; T = T2; break;
            default: W = W3; T = T3; break;
        }
        int n0 = gx * 32, k0 = gy * 32;
        int tx = threadIdx.x & 31, ty = threadIdx.x >> 5;   // ty: 0..7
        #pragma unroll
        for (int r = 0; r < 4; r++)
            tile[ty + r*8][tx] = W[(size_t)(k0 + ty + r*8) * EMBED + n0 + tx];
        __syncthreads();
        #pragma unroll
        for (int r = 0; r < 4; r++)
            T[(size_t)(n0 + ty + r*8) * EMBED + k0 + tx] = f2bf(tile[tx][ty + r*8]);
    }
}

// ---------------- shared 128x128 K-loop: triple-buffered, counted vmcnt (T4) ----------------
// Depth-2 prefetch; NEVER drains vmcnt to 0 in the main loop (raw s_barrier, no
// __syncthreads drain). LDS bank conflicts reduced 8-way -> 4-way via 16B-chunk
// XOR swizzle (chunk ^= row&3), applied on pre-swizzled global source + read side.
// Race-freedom: buf b read at iter t is rewritten earliest by stage at iter t+1
// targeting (t+3)%3 == b, which is gated behind the iter-t+1 barrier that all
// readers passed. vmcnt(4) before each barrier guarantees stage(t) landed.
// SWAP=false: acc = C fragment (regs = m axis); SWAP=true: acc = C^T (regs = n).
template<bool SWAP>
__device__ __forceinline__ void gemm_kloop(
        const short* __restrict__ A, const short* __restrict__ Bt,
        int m0, int n0, int t, short* Alds, short* Blds, f32x4 (*acc)[4]) {
    const int l = t & 63, w = t >> 6;
    const int wm = (w >> 1) * 64, wn = (w & 1) * 64;
    const int lr = l & 15, lg = l >> 4;
    const int arow = t >> 2, aseg = t & 3;
    const int ssw = (aseg ^ (arow & 3)) << 3;   // pre-swizzled source chunk (shorts)
    const int rsw = (lg ^ (lr & 3)) << 3;       // swizzled read chunk (shorts)

    const short* Ag = A  + (size_t)(m0 + arow) * EMBED + ssw;
    const short* Bg = Bt + (size_t)(n0 + arow) * EMBED + ssw;
    short* Al = Alds + arow * 32 + aseg * 8;
    short* Bl = Blds + arow * 32 + aseg * 8;

    auto stage = [&](int buf, int k0) {
        GLD_LDS(Ag + k0,                       Al + buf * 4096);
        GLD_LDS(Ag + (size_t)64 * EMBED + k0,  Al + buf * 4096 + 64 * 32);
        GLD_LDS(Bg + k0,                       Bl + buf * 4096);
        GLD_LDS(Bg + (size_t)64 * EMBED + k0,  Bl + buf * 4096 + 64 * 32);
    };

    auto iter = [&](int ti, int buf, bool last) {
        if (last) { asm volatile("s_waitcnt vmcnt(0)" ::: "memory"); }
        else      { asm volatile("s_waitcnt vmcnt(4)" ::: "memory"); }
        __builtin_amdgcn_sched_barrier(0);
        __builtin_amdgcn_s_barrier();
        if (ti + 2 < NKI) stage((ti + 2) % 3, (ti + 2) * 32);
        const short* Ab = Alds + buf * 4096;
        const short* Bb = Blds + buf * 4096;
        bf16x8 af[4], bfr[4];
        #pragma unroll
        for (int i = 0; i < 4; i++)
            af[i] = *reinterpret_cast<const bf16x8*>(Ab + (wm + i*16 + lr) * 32 + rsw);
        #pragma unroll
        for (int j = 0; j < 4; j++)
            bfr[j] = *reinterpret_cast<const bf16x8*>(Bb + (wn + j*16 + lr) * 32 + rsw);
        __builtin_amdgcn_s_setprio(1);
        #pragma unroll
        for (int i = 0; i < 4; i++)
            #pragma unroll
            for (int j = 0; j < 4; j++) {
                if (SWAP) acc[i][j] = MFMA32(bfr[j], af[i], acc[i][j]);
                else      acc[i][j] = MFMA32(af[i], bfr[j], acc[i][j]);
            }
        __builtin_amdgcn_s_setprio(0);
    };

    stage(0, 0);
    stage(1, 32);
    #pragma unroll
    for (int tt = 0; tt < NKI; tt += 3) {
        iter(tt,     0, false);
        iter(tt + 1, 1, false);
        iter(tt + 2, 2, tt + 2 == NKI - 1);
    }
}

// ---------------- fused QKV GEMM: [8192 x 768] @ [768 x 2304] ----------------
__global__ __launch_bounds__(256) void gemm_qkv_kernel(
        const short* __restrict__ A, const short* __restrict__ Bt,
        const float* __restrict__ bq, const float* __restrict__ bk,
        const float* __restrict__ bv,
        short* __restrict__ Qh, short* __restrict__ Kh, short* __restrict__ Vtg) {
    __shared__ short Alds[3 * 128 * 32];
    __shared__ short Blds[3 * 128 * 32];
    // XCD-bijective swizzle (1152 % 8 == 0), n-fastest inside each XCD chunk.
    const int id = blockIdx.x;
    const int flat = (id & 7) * 144 + (id >> 3);
    const int mi = flat / 18, ni = flat - mi * 18;
    const int m0 = mi * 128, n0 = ni * 128;

    const int t = threadIdx.x;
    const int l = t & 63, w = t >> 6;
    const int wm = (w >> 1) * 64, wn = (w & 1) * 64;
    const int lr = l & 15, lg = l >> 4;

    const int regb = n0 / 768;           // block-uniform (768 % 128 == 0)
    f32x4 acc[4][4] = {};

    if (regb < 2) {
        // Q/K: accumulate C^T so regs = hd axis -> packed 8B stores
        gemm_kloop<true>(A, Bt, m0, n0, t, Alds, Blds, acc);
        const float* bias = regb ? bk : bq;
        short* dst = regb ? Kh : Qh;
        const float scale = regb ? 1.0f : QSCALE;
        const int nbase = n0 - regb * 768;
        #pragma unroll
        for (int j = 0; j < 4; j++) {
            const int nf = nbase + wn + j * 16 + lg * 4;
            const float4 bl = *reinterpret_cast<const float4*>(bias + nf);
            const int h = nf >> 6, hd0 = nf & 63;
            #pragma unroll
            for (int i = 0; i < 4; i++) {
                const int m = m0 + wm + i * 16 + lr;
                const int bi = m >> 10, seq = m & 1023;
                s16x4 pk;
                pk[0] = f2bf((acc[i][j][0] + bl.x) * scale);
                pk[1] = f2bf((acc[i][j][1] + bl.y) * scale);
                pk[2] = f2bf((acc[i][j][2] + bl.z) * scale);
                pk[3] = f2bf((acc[i][j][3] + bl.w) * scale);
                *reinterpret_cast<s16x4*>(dst +
                    ((size_t)(bi * HEADS + h) * NSEQ + seq) * HDIM + hd0) = pk;
            }
        }
    } else {
        // V: normal orientation (regs = seq axis) -> packed stores into [B,H,64,N]
        gemm_kloop<false>(A, Bt, m0, n0, t, Alds, Blds, acc);
        #pragma unroll
        for (int j = 0; j < 4; j++) {
            const int nn = n0 + wn + j * 16 + lr - 1536;
            const int h = nn >> 6, hd = nn & 63;
            const float b = bv[nn];
            #pragma unroll
            for (int i = 0; i < 4; i++) {
                const int mbase = m0 + wm + i * 16 + lg * 4;
                const int bi = mbase >> 10, seq = mbase & 1023;
                s16x4 pk;
                #pragma unroll
                for (int r = 0; r < 4; r++) pk[r] = f2bf(acc[i][j][r] + b);
                *reinterpret_cast<s16x4*>(Vtg +
                    ((size_t)((bi * HEADS + h) * HDIM + hd)) * NSEQ + seq) = pk;
            }
        }
    }
}

// ---------------- output projection GEMM (C^T accumulation, float4 stores) ----------------
__global__ __launch_bounds__(256) void gemm_out_kernel(
        const short* __restrict__ A, const short* __restrict__ Bt,
        const float* __restrict__ bias, float* __restrict__ out) {
    __shared__ short Alds[3 * 128 * 32];
    __shared__ short Blds[3 * 128 * 32];
    // bijective XCD swizzle (384 % 8 == 0), n-fastest per XCD chunk
    const int id = blockIdx.x;
    const int flat = (id & 7) * 48 + (id >> 3);
    const int mi = flat / 6, ni = flat - mi * 6;
    const int m0 = mi * 128, n0 = ni * 128;
    const int t = threadIdx.x;
    const int l = t & 63, w = t >> 6;
    const int wm = (w >> 1) * 64, wn = (w & 1) * 64;
    const int lr = l & 15, lg = l >> 4;

    f32x4 acc[4][4] = {};
    gemm_kloop<true>(A, Bt, m0, n0, t, Alds, Blds, acc);

    #pragma unroll
    for (int j = 0; j < 4; j++) {
        const int nf = n0 + wn + j * 16 + lg * 4;
        const float4 bl = *reinterpret_cast<const float4*>(bias + nf);
        #pragma unroll
        for (int i = 0; i < 4; i++) {
            const int m = m0 + wm + i * 16 + lr;
            float4 o;
            o.x = acc[i][j][0] + bl.x;
            o.y = acc[i][j][1] + bl.y;
            o.z = acc[i][j][2] + bl.z;
            o.w = acc[i][j][3] + bl.w;
            *reinterpret_cast<float4*>(out + (size_t)m * EMBED + nf) = o;
        }
    }
}

// ---------------- flash attention: 2 q-tiles/wave, K/V-frag reuse ----------------
// Qh: pre-scaled by QSCALE (log2 domain). Kh: [96][1024][64]. Vtg: [96][64][1024].
__global__ __launch_bounds__(256, 3) void attn_kernel(
        const short* __restrict__ Qh, const short* __restrict__ Kh,
        const short* __restrict__ Vtg, short* __restrict__ ctx) {
    __shared__ short Klds[2][64 * 64];     // [key][hd], 16B-chunk XOR-swizzled by key&7
    __shared__ short Vlds[2][64 * 64];     // [hd][key], swizzled by hd&7
    __shared__ short Plds[4][2][16 * 64];  // per-wave, per-q-tile P[q][k], swizzled by q&7

    const int bid = blockIdx.x;
    const int bh = bid % BH;               // XCD affinity: q-blocks of a head share bid%8
    const int q0 = (bid / BH) * 128;
    const int t = threadIdx.x, l = t & 63, w = t >> 6;
    const int lr = l & 15, lg = l >> 4;
    const int pmask = lr & 7;
    const size_t headbase = (size_t)bh * NSEQ;

    // Q fragments for both q-tiles, registers for the whole kernel
    bf16x8 aq00, aq01, aq10, aq11;
    {
        const short* qb0 = Qh + (headbase + q0 + w * 16 + lr) * HDIM + lg * 8;
        aq00 = *reinterpret_cast<const bf16x8*>(qb0);
        aq01 = *reinterpret_cast<const bf16x8*>(qb0 + 32);
        const short* qb1 = qb0 + 64 * HDIM;
        aq10 = *reinterpret_cast<const bf16x8*>(qb1);
        aq11 = *reinterpret_cast<const bf16x8*>(qb1 + 32);
    }

    const int srow = t >> 3, sseg = t & 7;
    auto stage = [&](int bufb, int kt0) {
        #pragma unroll
        for (int p = 0; p < 2; p++) {
            int row = srow + p * 32;
            int sw = (sseg ^ (row & 7)) << 3;   // pre-swizzled global chunk (involution)
            GLD_LDS(Kh + (headbase + kt0 + row) * HDIM + sw,
                    &Klds[bufb][row * 64 + sseg * 8]);
            GLD_LDS(Vtg + (((size_t)(bh * HDIM + row)) << 10) + kt0 + sw,
                    &Vlds[bufb][row * 64 + sseg * 8]);
        }
    };

    f32x4 acc0[4] = {}, acc1[4] = {};
    float mrun0 = -1e30f, lrun0 = 0.f, mrun1 = -1e30f, lrun1 = 0.f;

    // online softmax in log2 domain; tree reductions; defer-max (T13)
    auto softmax = [&](f32x4* s, float& mrun, float& lrun, f32x4* acc) {
        float g0 = fmaxf(fmaxf(s[0][0], s[0][1]), fmaxf(s[0][2], s[0][3]));
        float g1 = fmaxf(fmaxf(s[1][0], s[1][1]), fmaxf(s[1][2], s[1][3]));
        float g2 = fmaxf(fmaxf(s[2][0], s[2][1]), fmaxf(s[2][2], s[2][3]));
        float g3 = fmaxf(fmaxf(s[3][0], s[3][1]), fmaxf(s[3][2], s[3][3]));
        float pm = fmaxf(fmaxf(g0, g1), fmaxf(g2, g3));
        pm = fmaxf(pm, __shfl_xor(pm, 16));
        pm = fmaxf(pm, __shfl_xor(pm, 32));
        if (!__all(pm - mrun <= 8.f)) {
            float mnew = fmaxf(mrun, pm);
            float alpha = fexp2(mrun - mnew);
            mrun = mnew;
            lrun *= alpha;
            #pragma unroll
            for (int r = 0; r < 4; r++) {
                float ar = __shfl(alpha, (lg << 4) | (lg * 4 + r));
                #pragma unroll
                for (int ht = 0; ht < 4; ht++) acc[ht][r] *= ar;
            }
        }
        #pragma unroll
        for (int kt = 0; kt < 4; kt++)
            #pragma unroll
            for (int r = 0; r < 4; r++)
                s[kt][r] = fexp2(s[kt][r] - mrun);
        float a0 = (s[0][0] + s[0][1]) + (s[0][2] + s[0][3]);
        float a1 = (s[1][0] + s[1][1]) + (s[1][2] + s[1][3]);
        float a2 = (s[2][0] + s[2][1]) + (s[2][2] + s[2][3]);
        float a3 = (s[3][0] + s[3][1]) + (s[3][2] + s[3][3]);
        float ts = (a0 + a1) + (a2 + a3);
        ts += __shfl_xor(ts, 16);
        ts += __shfl_xor(ts, 32);
        lrun += ts;
    };

    stage(0, 0);
    __syncthreads();

    int cur = 0;
    for (int it = 0; it < NSEQ / 64; ++it) {
        if (it + 1 < NSEQ / 64) stage(cur ^ 1, (it + 1) * 64);

        // S^T = K Q^T for both q-tiles; K-fragments loaded once, used twice
        f32x4 s0[4], s1[4];
        const short* Kb = Klds[cur];
        __builtin_amdgcn_s_setprio(1);
        #pragma unroll
        for (int kt = 0; kt < 4; kt++) {
            const short* kb = Kb + (kt * 16 + lr) * 64;
            bf16x8 ak0 = *reinterpret_cast<const bf16x8*>(kb + ((lg ^ pmask) << 3));
            bf16x8 ak1 = *reinterpret_cast<const bf16x8*>(kb + (((lg + 4) ^ pmask) << 3));
            f32x4 z0 = {}, z1 = {};
            z0 = MFMA32(ak0, aq00, z0);
            z1 = MFMA32(ak0, aq10, z1);
            z0 = MFMA32(ak1, aq01, z0);
            z1 = MFMA32(ak1, aq11, z1);
            s0[kt] = z0; s1[kt] = z1;
        }
        __builtin_amdgcn_s_setprio(0);

        softmax(s0, mrun0, lrun0, acc0);
        softmax(s1, mrun1, lrun1, acc1);

        // pack P -> per-wave per-tile LDS, A-operand layout, swizzled 8B writes
        short* pw0 = &Plds[w][0][0];
        short* pw1 = &Plds[w][1][0];
        #pragma unroll
        for (int kt = 0; kt < 4; kt++) {
            s16x4 pk0, pk1;
            #pragma unroll
            for (int r = 0; r < 4; r++) { pk0[r] = f2bf(s0[kt][r]); pk1[r] = f2bf(s1[kt][r]); }
            int chunk = kt * 2 + (lg >> 1);
            int off = lr * 64 + ((chunk ^ pmask) << 3) + ((lg & 1) << 2);
            *reinterpret_cast<s16x4*>(pw0 + off) = pk0;
            *reinterpret_cast<s16x4*>(pw1 + off) = pk1;
        }

        // PV: V-fragments loaded once, used for both q-tiles
        const short* Vb = Vlds[cur];
        #pragma unroll
        for (int kb = 0; kb < 2; kb++) {
            int poff = lr * 64 + (((kb * 4 + lg) ^ pmask) << 3);
            bf16x8 pa0 = *reinterpret_cast<const bf16x8*>(pw0 + poff);
            bf16x8 pa1 = *reinterpret_cast<const bf16x8*>(pw1 + poff);
            __builtin_amdgcn_s_setprio(1);
            #pragma unroll
            for (int ht = 0; ht < 4; ht++) {
                const short* vb = Vb + (ht * 16 + lr) * 64 + (((kb * 4 + lg) ^ pmask) << 3);
                bf16x8 bv = *reinterpret_cast<const bf16x8*>(vb);
                acc0[ht] = MFMA32(pa0, bv, acc0[ht]);
                acc1[ht] = MFMA32(pa1, bv, acc1[ht]);
            }
            __builtin_amdgcn_s_setprio(0);
        }

        __syncthreads();
        cur ^= 1;
    }

    // epilogue
    int b = bh / HEADS, h = bh % HEADS;
    #pragma unroll
    for (int r = 0; r < 4; r++) {
        int src = (lg << 4) | (lg * 4 + r);
        float linv0 = 1.f / __shfl(lrun0, src);
        float linv1 = 1.f / __shfl(lrun1, src);
        int q = q0 + w * 16 + lg * 4 + r;
        #pragma unroll
        for (int ht = 0; ht < 4; ht++) {
            ctx[((size_t)b * NSEQ + q) * EMBED + h * HDIM + ht * 16 + lr] =
                f2bf(acc0[ht][r] * linv0);
            ctx[((size_t)b * NSEQ + q + 64) * EMBED + h * HDIM + ht * 16 + lr] =
                f2bf(acc1[ht][r] * linv1);
        }
    }
}

// ---------------- launch ----------------

extern "C" void kernel_launch(void* const* d_in, const int* in_sizes, int n_in,
                              void* d_out, int out_size, void* d_ws, size_t ws_size,
                              hipStream_t stream) {
    (void)in_sizes; (void)n_in; (void)out_size; (void)ws_size;
    const float* x  = (const float*)d_in[0];
    const float* Wq = (const float*)d_in[1];
    const float* bq = (const float*)d_in[2];
    const float* Wk = (const float*)d_in[3];
    const float* bk = (const float*)d_in[4];
    const float* Wv = (const float*)d_in[5];
    const float* bv = (const float*)d_in[6];
    const float* Wo = (const float*)d_in[7];
    const float* bo = (const float*)d_in[8];
    float* out = (float*)d_out;

    char* ws = (char*)d_ws;
    size_t off = 0;
    short* xb  = (short*)(ws + off); off += (size_t)MROWS * EMBED * 2;
    short* Wtq = (short*)(ws + off); off += (size_t)EMBED * EMBED * 2;   // ┐ contiguous:
    short* Wtk = (short*)(ws + off); off += (size_t)EMBED * EMBED * 2;   // │ Bt = Wtq is
    short* Wtv = (short*)(ws + off); off += (size_t)EMBED * EMBED * 2;   // ┘ [2304][768]
    short* Wto = (short*)(ws + off); off += (size_t)EMBED * EMBED * 2;
    short* Qh  = (short*)(ws + off); off += (size_t)BH * NSEQ * HDIM * 2;
    short* Kh  = (short*)(ws + off); off += (size_t)BH * NSEQ * HDIM * 2;
    short* Vtg = (short*)(ws + off); off += (size_t)BH * NSEQ * HDIM * 2;
    short* ctx = (short*)(ws + off); off += (size_t)MROWS * EMBED * 2;

    prep_kernel<<<CVT_BLOCKS + 2304, 256, 0, stream>>>(
        x, xb, MROWS * EMBED, Wq, Wk, Wv, Wo, Wtq, Wtk, Wtv, Wto);

    gemm_qkv_kernel<<<(MROWS / 128) * (2304 / 128), 256, 0, stream>>>(
        xb, Wtq, bq, bk, bv, Qh, Kh, Vtg);

    attn_kernel<<<BH * (NSEQ / 128), 256, 0, stream>>>(Qh, Kh, Vtg, ctx);

    gemm_out_kernel<<<(MROWS / 128) * (EMBED / 128), 256, 0, stream>>>(ctx, Wto, bo, out);
}